// Round 6
// baseline (17918.358 us; speedup 1.0000x reference)
//
#include <hip/hip_runtime.h>
#include <cstdint>

#define Bb 32
#define Cc 512
#define Nn 384
#define Vv 600
#define Ee 256
#define Dd 512
#define Tt 192
#define Ss 191
#define EOS_TOK 130
#define BD (Bb*Dd)          // 16384
#define NBLK 256            // worker blocks; grid = NBLK+1 (block 0 = barrier server)
#define NTHR 512

// ---- ws layout (float offsets) ----  (r0/r3 proven layout)
#define OFF_TOK   0                      // int tok[Ss*Bb]
#define OFF_SHIFT 8192                   // float shift[1]
#define OFF_WV    8256                   // Bb*Nn*Dd = 6291456
#define OFF_HXT   (OFF_WV + 6291456)     // 2 * 512*32 (double-buffered, [d][b])
#define OFF_XO    (OFF_HXT + 32768)      // 512*32 o_prev transposed [d][b]
#define OFF_CX    (OFF_XO + 16384)       // (unused; cx lives in LDS)
#define OFF_DEN   (OFF_CX + 16384)       // denom[t][b] 191*32 (pad 8192)
#define OFF_Q     (OFF_DEN + 8192)       // q[b][d] 32*512
#define OFF_CTX   (OFF_Q + 16384)        // ctxT[c][b] 512*32
#define OFF_OBUF  (OFF_CTX + 16384)      // 192*BD; slot t+1 front 8192 doubles as embx[t]
#define OFF_BAR   (OFF_OBUF + 192*16384) // flags[257*16] + genv[32*16]

#define LOGITS_SZ (Bb*Ss*Vv)  // 3667200
#define ALPHA_SZ  (Bb*Ss*Nn)  // 2347008

__device__ __forceinline__ float sigm_(float x) {
    float e = __expf(-x);
    return __builtin_amdgcn_rcpf(1.0f + e);
}
__device__ __forceinline__ float tanh_(float x) {
    float xc = fminf(15.0f, fmaxf(-15.0f, x));
    float e = __expf(2.0f * xc);
    return (e - 1.0f) * __builtin_amdgcn_rcpf(e + 1.0f);
}

// Write-through device store (sc1): at LLC once vmcnt retires; __syncthreads
// drains vmcnt, so no release fence is ever needed.
__device__ __forceinline__ void st_dev(float* p, float v) {
    __hip_atomic_store(p, v, __ATOMIC_RELAXED, __HIP_MEMORY_SCOPE_AGENT);
}
// 8-byte coherent load (sc1 bypass, relaxed).
__device__ __forceinline__ float2 ld2_dev(const float* p) {
    unsigned long long u = __hip_atomic_load((const unsigned long long*)p,
                                             __ATOMIC_RELAXED,
                                             __HIP_MEMORY_SCOPE_AGENT);
    float2 f;
    f.x = __uint_as_float((unsigned int)u);
    f.y = __uint_as_float((unsigned int)(u >> 32));
    return f;
}

// Split barrier with a DEDICATED server block (block 0 of the grid):
//   arrive: __syncthreads (drains sc1 stores) + one flag store per worker.
//   wait:   poll one of 32 replicated release lines posted by the server.
// The server never computes, so release latency is never delayed by any
// worker's pre-work (the r2 failure mode, eliminated by construction).
__device__ __forceinline__ void w_arrive(int* flags, int ibar) {
    __syncthreads();
    if (threadIdx.x == 0)
        __hip_atomic_store(&flags[blockIdx.x * 16], ibar + 1, __ATOMIC_RELAXED,
                           __HIP_MEMORY_SCOPE_AGENT);
}
__device__ __forceinline__ void w_wait(int* genv, int wid, int ibar) {
    const int target = ibar + 1;
    if (threadIdx.x == 0) {
        int* g = &genv[(wid >> 3) * 16];
        while (__hip_atomic_load(g, __ATOMIC_RELAXED,
                                 __HIP_MEMORY_SCOPE_AGENT) < target)
            __builtin_amdgcn_s_sleep(2);
    }
    __syncthreads();
}

// S0: zero state/flags/denoms, token sequence, exp-shift = sum|v|.
__global__ void k_setup(const int* __restrict__ tgt, const float* __restrict__ vv,
                        float* zbase, int* bar, int* tok, float* shiftbuf) {
    int gid = blockIdx.x * 256 + threadIdx.x;
    for (int i = gid; i < 73728; i += 96 * 256) zbase[i] = 0.f;
    if (gid < 4864) bar[gid] = 0;   // flags[257*16] + genv[32*16]
    if (blockIdx.x == 0) {
        __shared__ int is64;
        if (threadIdx.x == 0) {
            int a = 1;
            for (int k = 0; k < 32; ++k) if (tgt[2 * k + 1] != 0) a = 0;
            is64 = a;
        }
        __syncthreads();
        int b = threadIdx.x;
        if (b < Bb) {
            int fin = 0;
            tok[0 * Bb + b] = 0;
            for (int s = 1; s < Ss; ++s) {
                int li = b * Tt + s;
                int nt = is64 ? tgt[2 * li] : tgt[li];
                if (nt == EOS_TOK) fin = 1;
                tok[s * Bb + b] = fin ? 0 : nt;
            }
        }
    }
    if (blockIdx.x == 1) {
        __shared__ float sred[256];
        int tid = threadIdx.x;
        sred[tid] = fabsf(vv[tid]) + fabsf(vv[tid + 256]);
        __syncthreads();
        for (int s = 128; s > 0; s >>= 1) {
            if (tid < s) sred[tid] += sred[tid + s];
            __syncthreads();
        }
        if (tid == 0) shiftbuf[0] = sred[0];
    }
}

// S1: gather embeddings for all steps into obuf slot fronts: [t][k][b]
__global__ void k_embx(const float* __restrict__ emb, const int* __restrict__ tok,
                       float* __restrict__ obuf) {
    int i = blockIdx.x * 256 + threadIdx.x;
    if (i < Ss * 8192) {
        int t = i >> 13, e = i & 8191;
        int k = e >> 5, b = e & 31;
        obuf[(size_t)(t + 1) * BD + e] = emb[(size_t)tok[t * 32 + b] * Ee + k];
    }
}

// S2: Wv[b,n,d] = sum_c enc[b,n,c] * W_v[c,d]
__global__ void k_wv(const float* __restrict__ enc, const float* __restrict__ Wv_w,
                     float* __restrict__ Wv) {
    int b = blockIdx.x / 24, nt = blockIdx.x % 24, n0 = nt * 16;
    __shared__ float encL[16 * 512];
    for (int i = 0; i < 32; ++i) {
        int e = threadIdx.x + i * 256;
        int ni = e >> 9, c = e & 511;
        encL[e] = enc[((b * Nn) + (n0 + ni)) * Cc + c];
    }
    __syncthreads();
    int d0 = threadIdx.x, d1 = threadIdx.x + 256;
    float a0[16], a1[16];
#pragma unroll
    for (int i = 0; i < 16; ++i) { a0[i] = 0.f; a1[i] = 0.f; }
    for (int c = 0; c < 512; ++c) {
        float w0 = Wv_w[c * Dd + d0], w1 = Wv_w[c * Dd + d1];
#pragma unroll
        for (int i = 0; i < 16; ++i) {
            float ev = encL[i * 512 + c];
            a0[i] += ev * w0; a1[i] += ev * w1;
        }
    }
#pragma unroll
    for (int i = 0; i < 16; ++i) {
        Wv[((b * Nn) + (n0 + i)) * Dd + d0] = a0[i];
        Wv[((b * Nn) + (n0 + i)) * Dd + d1] = a1[i];
    }
}

// Persistent decode: 257 blocks x 512 threads.
// Block 0 = pure barrier server. Workers (wid = bid-1) own dims {2wid,2wid+1},
// weights LDS-resident, 4 barriers/step with 2 of them latency-hidden:
//  - A(t): emb+hx GEMV rows run BEFORE waiting on F(t-1); o rows after.
//  - F(t): hx half runs BEFORE waiting on DE(t); ctx half after.
// LDS trimmed to 69.9KB and VGPR capped at 128 so 2 blocks fit one CU
// (grid 257 > 256 CUs requires it for co-residency).
__global__ __launch_bounds__(NTHR, 4) void k_decode(
    const float* __restrict__ enc, const float* __restrict__ W_ih,
    const float* __restrict__ b_ih, const float* __restrict__ W_hh,
    const float* __restrict__ b_hh, const float* __restrict__ W_h,
    const float* __restrict__ vv, const float* __restrict__ W_c,
    const float* __restrict__ b_c, const float* __restrict__ Wv,
    const float* __restrict__ shiftbuf,
    float* __restrict__ hxT, float* __restrict__ xo,
    float* __restrict__ den, float* __restrict__ q, float* __restrict__ ctxT,
    float* __restrict__ obuf, float* __restrict__ alpha_e, int* bar)
{
    __shared__ float Wg[1280 * 8];    // gates cols [k][g*2+dd]    40960B
    __shared__ float Whx[512 * 2];    // W_h cols   [d][dd]         4096B
    __shared__ float Wc[1024 * 2];    // W_c cols   [k][dd]         8192B
    __shared__ float scratch[4096];   // phase-local (2-round A)   16384B
    __shared__ float cxL[64];         // block-private cell state

    int* flags = bar;
    int* genv  = bar + 4352;

    const int tid = threadIdx.x, bid = blockIdx.x;

    // ---------------- barrier server (block 0) ----------------
    if (bid == 0) {
        if (tid < 64) {
            int l = tid * 4;
            for (int ibb = 0; ibb < 4 * Ss; ++ibb) {
                const int target = ibb + 1;
                for (;;) {
                    int f0 = __hip_atomic_load(&flags[(l + 1) * 16], __ATOMIC_RELAXED,
                                               __HIP_MEMORY_SCOPE_AGENT);
                    int f1 = __hip_atomic_load(&flags[(l + 2) * 16], __ATOMIC_RELAXED,
                                               __HIP_MEMORY_SCOPE_AGENT);
                    int f2 = __hip_atomic_load(&flags[(l + 3) * 16], __ATOMIC_RELAXED,
                                               __HIP_MEMORY_SCOPE_AGENT);
                    int f3 = __hip_atomic_load(&flags[(l + 4) * 16], __ATOMIC_RELAXED,
                                               __HIP_MEMORY_SCOPE_AGENT);
                    if (__all(f0 >= target && f1 >= target &&
                              f2 >= target && f3 >= target)) break;
                    __builtin_amdgcn_s_sleep(1);
                }
                if (tid < 32)
                    __hip_atomic_store(&genv[tid * 16], target,
                                       __ATOMIC_RELAXED, __HIP_MEMORY_SCOPE_AGENT);
            }
        }
        return;
    }

    // ---------------- worker ----------------
    const int wid = bid - 1;
    const int lane = tid & 63;
    const int d0 = wid * 2;
    const int bp = tid & 15;          // b-pair: b = 2bp, 2bp+1
    const int ab = wid >> 3;          // DE: attention batch
    const int n0 = (wid & 7) * 48;    // DE: n-slice
    const int w  = tid >> 6;          // wave id

    // ---- one-time weight staging into LDS ----
    for (int k = tid; k < 1280; k += NTHR) {
        const float* src = (k < 768) ? (W_ih + (size_t)k * 2048)
                                     : (W_hh + (size_t)(k - 768) * 2048);
#pragma unroll
        for (int g = 0; g < 4; ++g) {
            Wg[k * 8 + g * 2 + 0] = src[g * 512 + d0 + 0];
            Wg[k * 8 + g * 2 + 1] = src[g * 512 + d0 + 1];
        }
    }
    {
        int d = tid;  // NTHR == 512
        Whx[d * 2 + 0] = W_h[(size_t)d * 512 + d0 + 0];
        Whx[d * 2 + 1] = W_h[(size_t)d * 512 + d0 + 1];
    }
    for (int k = tid; k < 1024; k += NTHR) {
        Wc[k * 2 + 0] = W_c[(size_t)k * 512 + d0 + 0];
        Wc[k * 2 + 1] = W_c[(size_t)k * 512 + d0 + 1];
    }
    if (tid < 64) cxL[tid] = 0.f;
    float v8[8];
#pragma unroll
    for (int i = 0; i < 8; ++i) v8[i] = vv[lane * 8 + i];
    float4 wva[6], wvb[6];            // t-invariant Wv fragment (48 floats)
#pragma unroll
    for (int r = 0; r < 6; ++r) {
        const float* wv = Wv + ((size_t)(ab * Nn + n0 + w * 6 + r)) * 512 + lane * 8;
        wva[r] = *(const float4*)wv;
        wvb[r] = *(const float4*)(wv + 4);
    }
    const float SHIFT = shiftbuf[0];
    float bsum0 = 0.f, bsum1 = 0.f, bsum2 = 0.f, bsum3 = 0.f, bcv = 0.f;
    if (tid < 64) {
        int dd = tid >> 5;
        int d = d0 + dd;
        bsum0 = b_ih[0 * 512 + d] + b_hh[0 * 512 + d];
        bsum1 = b_ih[1 * 512 + d] + b_hh[1 * 512 + d];
        bsum2 = b_ih[2 * 512 + d] + b_hh[2 * 512 + d];
        bsum3 = b_ih[3 * 512 + d] + b_hh[3 * 512 + d];
        bcv = b_c[d];
    }
    __syncthreads();

    for (int t = 0; t < Ss; ++t) {
        const int rd = t & 1, wr = 1 - rd;
        const float* hxT_rd = hxT + rd * 16384;
        float*       hxT_wr = hxT + wr * 16384;

        // ---------- Phase A: gates (split: emb+hx pre-wait, o post-wait) ----------
        {
            const float* embx_t = obuf + (size_t)(t + 1) * BD;  // [k][b], k<256
            const float* xo2 = xo - 256 * 32;
            const float* hx2 = hxT_rd - 768 * 32;
            int ks = tid >> 4;           // 32 k-chunks of 40
            int k0 = ks * 40;
            float ax[8], ay[8];
#pragma unroll
            for (int i = 0; i < 8; ++i) { ax[i] = 0.f; ay[i] = 0.f; }
            if (t) {
                // pre-wait: emb (static) + hx(t-1) (ready since bar A(t-1))
#pragma unroll
                for (int kb = 0; kb < 5; ++kb) {
                    int kbase = k0 + kb * 8;
                    if (kbase >= 256 && kbase < 768) continue;   // o rows later
                    const float* base = (kbase < 256) ? embx_t : hx2;
                    float2 xv[8];
#pragma unroll
                    for (int j = 0; j < 8; ++j)
                        xv[j] = ld2_dev(base + (kbase + j) * 32 + 2 * bp);
#pragma unroll
                    for (int j = 0; j < 8; ++j) {
                        int k = kbase + j;
                        float4 wA = *(const float4*)&Wg[k * 8];
                        float4 wB = *(const float4*)&Wg[k * 8 + 4];
                        ax[0] += xv[j].x * wA.x; ay[0] += xv[j].y * wA.x;
                        ax[1] += xv[j].x * wA.y; ay[1] += xv[j].y * wA.y;
                        ax[2] += xv[j].x * wA.z; ay[2] += xv[j].y * wA.z;
                        ax[3] += xv[j].x * wA.w; ay[3] += xv[j].y * wA.w;
                        ax[4] += xv[j].x * wB.x; ay[4] += xv[j].y * wB.x;
                        ax[5] += xv[j].x * wB.y; ay[5] += xv[j].y * wB.y;
                        ax[6] += xv[j].x * wB.z; ay[6] += xv[j].y * wB.z;
                        ax[7] += xv[j].x * wB.w; ay[7] += xv[j].y * wB.w;
                    }
                }
                w_wait(genv, wid, 4 * t - 1);    // F(t-1) done everywhere
                // post-wait: o_prev rows
#pragma unroll
                for (int kb = 0; kb < 5; ++kb) {
                    int kbase = k0 + kb * 8;
                    if (kbase < 256 || kbase >= 768) continue;
                    float2 xv[8];
#pragma unroll
                    for (int j = 0; j < 8; ++j)
                        xv[j] = ld2_dev(xo2 + (kbase + j) * 32 + 2 * bp);
#pragma unroll
                    for (int j = 0; j < 8; ++j) {
                        int k = kbase + j;
                        float4 wA = *(const float4*)&Wg[k * 8];
                        float4 wB = *(const float4*)&Wg[k * 8 + 4];
                        ax[0] += xv[j].x * wA.x; ay[0] += xv[j].y * wA.x;
                        ax[1] += xv[j].x * wA.y; ay[1] += xv[j].y * wA.y;
                        ax[2] += xv[j].x * wA.z; ay[2] += xv[j].y * wA.z;
                        ax[3] += xv[j].x * wA.w; ay[3] += xv[j].y * wA.w;
                        ax[4] += xv[j].x * wB.x; ay[4] += xv[j].y * wB.x;
                        ax[5] += xv[j].x * wB.y; ay[5] += xv[j].y * wB.y;
                        ax[6] += xv[j].x * wB.z; ay[6] += xv[j].y * wB.z;
                        ax[7] += xv[j].x * wB.w; ay[7] += xv[j].y * wB.w;
                    }
                }
            }
            // 2-round reduce into half-size scratch (16KB)
            if (tid < 256) {
#pragma unroll
                for (int c = 0; c < 8; ++c) {
                    scratch[(ks * 8 + c) * 32 + 2 * bp]     = ax[c];
                    scratch[(ks * 8 + c) * 32 + 2 * bp + 1] = ay[c];
                }
            }
            __syncthreads();
            if (tid >= 256) {
#pragma unroll
                for (int c = 0; c < 8; ++c) {
                    scratch[((ks - 16) * 8 + c) * 32 + 2 * bp]     += ax[c];
                    scratch[((ks - 16) * 8 + c) * 32 + 2 * bp + 1] += ay[c];
                }
            }
            __syncthreads();
            if (tid < 256) {
                int col = tid >> 5, b2 = tid & 31;
                float s = 0.f;
#pragma unroll
                for (int k2 = 0; k2 < 16; ++k2) s += scratch[(k2 * 8 + col) * 32 + b2];
                scratch[col * 32 + b2] = s;   // in-place: slot read only by this thread
            }
            __syncthreads();
            if (tid < 64) {
                int dd = tid >> 5, b2 = tid & 31;
                float gi = scratch[(0 * 2 + dd) * 32 + b2] + bsum0;
                float gf = scratch[(1 * 2 + dd) * 32 + b2] + bsum1;
                float gg = scratch[(2 * 2 + dd) * 32 + b2] + bsum2;
                float go = scratch[(3 * 2 + dd) * 32 + b2] + bsum3;
                float c = sigm_(gf) * cxL[tid] + sigm_(gi) * tanh_(gg);
                cxL[tid] = c;
                st_dev(&hxT_wr[(d0 + dd) * 32 + b2], sigm_(go) * tanh_(c));
            }
        }
        w_arrive(flags, 4 * t);

        // ---------- Phase C: q = hx @ W_h (2 cols) + zero ctxT slice ----------
        w_wait(genv, wid, 4 * t);
        {
            if (tid < 64)
                st_dev(&ctxT[wid * 64 + tid], 0.f);
            int dc = tid >> 4;            // 32 d-chunks of 16
            int dbase = dc * 16;
            float a00 = 0.f, a01 = 0.f, a10 = 0.f, a11 = 0.f;
#pragma unroll
            for (int db = 0; db < 2; ++db) {
                float2 hv[8];
#pragma unroll
                for (int j = 0; j < 8; ++j)
                    hv[j] = ld2_dev(hxT_wr + (dbase + db * 8 + j) * 32 + 2 * bp);
#pragma unroll
                for (int j = 0; j < 8; ++j) {
                    int d = dbase + db * 8 + j;
                    float w0 = Whx[d * 2 + 0], w1 = Whx[d * 2 + 1];
                    a00 += hv[j].x * w0; a10 += hv[j].y * w0;
                    a01 += hv[j].x * w1; a11 += hv[j].y * w1;
                }
            }
            scratch[(dc * 2 + 0) * 32 + 2 * bp]     = a00;
            scratch[(dc * 2 + 0) * 32 + 2 * bp + 1] = a10;
            scratch[(dc * 2 + 1) * 32 + 2 * bp]     = a01;
            scratch[(dc * 2 + 1) * 32 + 2 * bp + 1] = a11;
            __syncthreads();
            if (tid < 64) {
                int jj = tid >> 5, b2 = tid & 31;
                float s = 0.f;
#pragma unroll
                for (int d2 = 0; d2 < 32; ++d2) s += scratch[(d2 * 2 + jj) * 32 + b2];
                st_dev(&q[b2 * 512 + d0 + jj], s);
            }
        }
        w_arrive(flags, 4 * t + 1);

        // ---------- Phase DE: scores + exp(shifted) + ctx atomics ----------
        w_wait(genv, wid, 4 * t + 1);
        {
            float* esc = scratch;            // 48 e-values
            float q8[8];
#pragma unroll
            for (int j = 0; j < 4; ++j) {
                float2 qv = ld2_dev(&q[ab * 512 + lane * 8 + 2 * j]);
                q8[2 * j] = qv.x; q8[2 * j + 1] = qv.y;
            }
#pragma unroll
            for (int r = 0; r < 6; ++r) {
                float s = v8[0] * tanh_(q8[0] + wva[r].x) + v8[1] * tanh_(q8[1] + wva[r].y)
                        + v8[2] * tanh_(q8[2] + wva[r].z) + v8[3] * tanh_(q8[3] + wva[r].w)
                        + v8[4] * tanh_(q8[4] + wvb[r].x) + v8[5] * tanh_(q8[5] + wvb[r].y)
                        + v8[6] * tanh_(q8[6] + wvb[r].z) + v8[7] * tanh_(q8[7] + wvb[r].w);
#pragma unroll
                for (int off = 32; off > 0; off >>= 1)
                    s += __shfl_down(s, off, 64);
                if (lane == 0) esc[w * 6 + r] = __expf(s - SHIFT);
            }
            __syncthreads();
            if (tid < 48)
                alpha_e[((size_t)ab * Ss + t) * Nn + n0 + tid] = esc[tid];
            if (tid == 0) {
                float sd = 0.f;
                for (int i = 0; i < 48; ++i) sd += esc[i];
                atomicAdd(&den[t * 32 + ab], sd);
            }
            float acc = 0.f;
#pragma unroll 8
            for (int i = 0; i < 48; ++i)
                acc += esc[i] * enc[((size_t)(ab * Nn + n0 + i)) * 512 + tid];  // cached
            atomicAdd(&ctxT[tid * 32 + ab], acc);
        }
        w_arrive(flags, 4 * t + 2);

        // ---------- Phase F: o_t (split: hx half pre-wait, ctx half post-wait) ----------
        {
            int kc = tid >> 4;            // 32 k-chunks of 32 (16 hx + 16 ctx)
            int kb0 = kc * 32;
            float a00 = 0.f, a01 = 0.f, a10 = 0.f, a11 = 0.f;
            if (kc < 16) {                // hx half (ready since bar A(t))
#pragma unroll
                for (int kb = 0; kb < 4; ++kb) {
                    float2 xv[8];
#pragma unroll
                    for (int j = 0; j < 8; ++j)
                        xv[j] = ld2_dev(hxT_wr + (kb0 + kb * 8 + j) * 32 + 2 * bp);
#pragma unroll
                    for (int j = 0; j < 8; ++j) {
                        int k = kb0 + kb * 8 + j;
                        float w0 = Wc[k * 2 + 0], w1 = Wc[k * 2 + 1];
                        a00 += xv[j].x * w0; a10 += xv[j].y * w0;
                        a01 += xv[j].x * w1; a11 += xv[j].y * w1;
                    }
                }
            }
            w_wait(genv, wid, 4 * t + 2);     // DE done: ctx/den ready
            if (kc >= 16) {
                const float* src = ctxT - 512 * 32;
                float2 dp = ld2_dev(&den[t * 32 + 2 * bp]);
                float dx = 1.0f / dp.x, dy = 1.0f / dp.y;
#pragma unroll
                for (int kb = 0; kb < 4; ++kb) {
                    float2 xv[8];
#pragma unroll
                    for (int j = 0; j < 8; ++j)
                        xv[j] = ld2_dev(src + (kb0 + kb * 8 + j) * 32 + 2 * bp);
#pragma unroll
                    for (int j = 0; j < 8; ++j) {
                        int k = kb0 + kb * 8 + j;
                        float w0 = Wc[k * 2 + 0], w1 = Wc[k * 2 + 1];
                        a00 += xv[j].x * w0; a10 += xv[j].y * w0;
                        a01 += xv[j].x * w1; a11 += xv[j].y * w1;
                    }
                }
                a00 *= dx; a01 *= dx; a10 *= dy; a11 *= dy;
            }
            scratch[(kc * 2 + 0) * 32 + 2 * bp]     = a00;
            scratch[(kc * 2 + 0) * 32 + 2 * bp + 1] = a10;
            scratch[(kc * 2 + 1) * 32 + 2 * bp]     = a01;
            scratch[(kc * 2 + 1) * 32 + 2 * bp + 1] = a11;
            __syncthreads();
            if (tid < 64) {
                int dd = tid >> 5, b2 = tid & 31;
                float s = bcv;
#pragma unroll
                for (int k2 = 0; k2 < 32; ++k2) s += scratch[(k2 * 2 + dd) * 32 + b2];
                float o = tanh_(s);
                st_dev(&xo[(d0 + dd) * 32 + b2], o);
                obuf[(size_t)(t + 1) * BD + b2 * 512 + d0 + dd] = o;  // read post-kernel
            }
        }
        w_arrive(flags, 4 * t + 3);
    }
}

// Deferred logits GEMM.
__global__ void k_logits(const float* __restrict__ obuf, const float* __restrict__ W_out,
                         const float* __restrict__ b_out, float* __restrict__ out_logits) {
    int b = blockIdx.x / 24, tt = blockIdx.x % 24;
    int t0 = tt * 8;
    int tmax = min(8, Ss - t0);
    __shared__ float oL[8 * 512];
    int tid = threadIdx.x;
    for (int i = 0; i < 16; ++i) {
        int e = tid + i * 256;
        int ti = e >> 9, d = e & 511;
        oL[e] = (ti < tmax) ? obuf[(size_t)(t0 + ti + 1) * BD + b * Dd + d] : 0.f;
    }
    __syncthreads();
    int v0 = tid, v1 = tid + 256, v2 = tid + 512;
    bool h2 = (v2 < Vv);
    int v2c = h2 ? v2 : 0;
    float acc[3][8];
#pragma unroll
    for (int s = 0; s < 3; ++s)
#pragma unroll
        for (int ti = 0; ti < 8; ++ti) acc[s][ti] = 0.f;
    for (int d = 0; d < 512; ++d) {
        float w0 = W_out[d * Vv + v0];
        float w1 = W_out[d * Vv + v1];
        float w2 = W_out[d * Vv + v2c];
#pragma unroll
        for (int ti = 0; ti < 8; ++ti) {
            float o = oL[ti * 512 + d];
            acc[0][ti] += o * w0; acc[1][ti] += o * w1; acc[2][ti] += o * w2;
        }
    }
    for (int ti = 0; ti < tmax; ++ti) {
        size_t base = (size_t)b * (Ss * Vv) + (size_t)(t0 + ti) * Vv;
        out_logits[base + v0] = acc[0][ti] + b_out[v0];
        out_logits[base + v1] = acc[1][ti] + b_out[v1];
        if (h2) out_logits[base + v2] = acc[2][ti] + b_out[v2];
    }
}

// Normalize alphas: alpha /= denom[b,t]
__global__ void k_anorm(float* __restrict__ alph, const float* __restrict__ den) {
    int i = blockIdx.x * 256 + threadIdx.x;
    if (i < ALPHA_SZ) {
        int bt = i / Nn;
        int t = bt % Ss, b = bt / Ss;
        alph[i] = alph[i] / den[t * 32 + b];
    }
}

extern "C" void kernel_launch(void* const* d_in, const int* in_sizes, int n_in,
                              void* d_out, int out_size, void* d_ws, size_t ws_size,
                              hipStream_t stream) {
    const float* enc   = (const float*)d_in[0];
    const int*   tgt   = (const int*)d_in[1];
    const float* emb   = (const float*)d_in[2];
    const float* W_ih  = (const float*)d_in[3];
    const float* b_ih  = (const float*)d_in[4];
    const float* W_hh  = (const float*)d_in[5];
    const float* b_hh  = (const float*)d_in[6];
    const float* W_h   = (const float*)d_in[7];
    const float* W_v   = (const float*)d_in[8];
    const float* vv    = (const float*)d_in[9];
    const float* W_c   = (const float*)d_in[10];
    const float* b_c   = (const float*)d_in[11];
    const float* W_out = (const float*)d_in[12];
    const float* b_out = (const float*)d_in[13];

    float* wsf   = (float*)d_ws;
    int*   tok   = (int*)d_ws;
    float* shiftb= wsf + OFF_SHIFT;
    float* Wv    = wsf + OFF_WV;
    float* hxT   = wsf + OFF_HXT;
    float* xo    = wsf + OFF_XO;
    float* den   = wsf + OFF_DEN;
    float* q     = wsf + OFF_Q;
    float* ctxT  = wsf + OFF_CTX;
    float* obuf  = wsf + OFF_OBUF;
    int*   bar   = (int*)(wsf + OFF_BAR);

    float* out_logits = (float*)d_out;
    float* out_alphas = (float*)d_out + LOGITS_SZ;

    k_setup<<<96, 256, 0, stream>>>(tgt, vv, hxT, bar, tok, shiftb);
    k_embx<<<(Ss * 8192 + 255) / 256, 256, 0, stream>>>(emb, tok, obuf);
    k_wv<<<768, 256, 0, stream>>>(enc, W_v, Wv);
    k_decode<<<NBLK + 1, NTHR, 0, stream>>>(enc, W_ih, b_ih, W_hh, b_hh, W_h, vv,
                                            W_c, b_c, Wv, shiftb,
                                            hxT, xo, den, q, ctxT, obuf,
                                            out_alphas, bar);
    k_logits<<<768, 256, 0, stream>>>(obuf, W_out, b_out, out_logits);
    k_anorm<<<(ALPHA_SZ + 255) / 256, 256, 0, stream>>>(out_alphas, den);
}

// Round 7
// 9266.030 us; speedup vs baseline: 1.9338x; 1.9338x over previous
//
#include <hip/hip_runtime.h>
#include <cstdint>

#define Bb 32
#define Cc 512
#define Nn 384
#define Vv 600
#define Ee 256
#define Dd 512
#define Tt 192
#define Ss 191
#define EOS_TOK 130
#define BD (Bb*Dd)          // 16384
#define NBLK 256
#define NTHR 512

// ---- ws layout (float offsets) ----  (r0/r3 proven layout)
#define OFF_TOK   0                      // int tok[Ss*Bb]
#define OFF_SHIFT 8192                   // float shift[1]
#define OFF_WV    8256                   // Bb*Nn*Dd = 6291456
#define OFF_HXT   (OFF_WV + 6291456)     // 2 * 512*32 (double-buffered, [d][b])
#define OFF_XO    (OFF_HXT + 32768)      // 512*32 o_prev transposed [d][b]
#define OFF_CX    (OFF_XO + 16384)       // (unused; cx lives in LDS)
#define OFF_DEN   (OFF_CX + 16384)       // denom[t][b] 191*32 (pad 8192)
#define OFF_Q     (OFF_DEN + 8192)       // q[b][d] 32*512
#define OFF_CTX   (OFF_Q + 16384)        // ctxT[c][b] 512*32
#define OFF_OBUF  (OFF_CTX + 16384)      // 192*BD; slot t+1 front 8192 doubles as embx[t]
#define OFF_BAR   (OFF_OBUF + 192*16384) // flags[256*16]

#define LOGITS_SZ (Bb*Ss*Vv)  // 3667200
#define ALPHA_SZ  (Bb*Ss*Nn)  // 2347008

__device__ __forceinline__ float sigm_(float x) {
    float e = __expf(-x);
    return __builtin_amdgcn_rcpf(1.0f + e);
}
__device__ __forceinline__ float tanh_(float x) {
    float xc = fminf(15.0f, fmaxf(-15.0f, x));
    float e = __expf(2.0f * xc);
    return (e - 1.0f) * __builtin_amdgcn_rcpf(e + 1.0f);
}

// Write-through device store (sc1): at LLC once vmcnt retires; __syncthreads
// drains vmcnt, so no release fence is ever needed.
__device__ __forceinline__ void st_dev(float* p, float v) {
    __hip_atomic_store(p, v, __ATOMIC_RELAXED, __HIP_MEMORY_SCOPE_AGENT);
}
// 8-byte coherent load (sc1 bypass, relaxed).
__device__ __forceinline__ float2 ld2_dev(const float* p) {
    unsigned long long u = __hip_atomic_load((const unsigned long long*)p,
                                             __ATOMIC_RELAXED,
                                             __HIP_MEMORY_SCOPE_AGENT);
    float2 f;
    f.x = __uint_as_float((unsigned int)u);
    f.y = __uint_as_float((unsigned int)(u >> 32));
    return f;
}

// ALL-POLL split barrier (no aggregator, no release hop):
//   arrive: __syncthreads (drains sc1 stores) + one flag store per block.
//   wait:   EVERY block's wave 0 polls all 256 arrival flags directly
//           (4 lines/lane x 64 lanes = one LLC round per iteration).
// Flags are monotonically increasing, so a fast block storing its next-barrier
// value never breaks a slow block's `>= target` test. Latency per barrier =
// slowest-arrival + one LLC poll round, vs arrival + aggregator-detect +
// release-store + worker-detect in the old protocol.
__device__ __forceinline__ void bar_arrive(int* flags, int ibar) {
    __syncthreads();
    if (threadIdx.x == 0)
        __hip_atomic_store(&flags[blockIdx.x * 16], ibar + 1, __ATOMIC_RELAXED,
                           __HIP_MEMORY_SCOPE_AGENT);
}
__device__ __forceinline__ void bar_wait(int* flags, int ibar) {
    const int target = ibar + 1;
    if (threadIdx.x < 64) {
        int l = threadIdx.x * 4;
        for (;;) {
            int f0 = __hip_atomic_load(&flags[(l + 0) * 16], __ATOMIC_RELAXED,
                                       __HIP_MEMORY_SCOPE_AGENT);
            int f1 = __hip_atomic_load(&flags[(l + 1) * 16], __ATOMIC_RELAXED,
                                       __HIP_MEMORY_SCOPE_AGENT);
            int f2 = __hip_atomic_load(&flags[(l + 2) * 16], __ATOMIC_RELAXED,
                                       __HIP_MEMORY_SCOPE_AGENT);
            int f3 = __hip_atomic_load(&flags[(l + 3) * 16], __ATOMIC_RELAXED,
                                       __HIP_MEMORY_SCOPE_AGENT);
            if (__all(f0 >= target && f1 >= target &&
                      f2 >= target && f3 >= target)) break;
            __builtin_amdgcn_s_sleep(1);
        }
    }
    __syncthreads();
}

// S0: zero state/flags/denoms, token sequence, exp-shift = sum|v|.
__global__ void k_setup(const int* __restrict__ tgt, const float* __restrict__ vv,
                        float* zbase, int* bar, int* tok, float* shiftbuf) {
    int gid = blockIdx.x * 256 + threadIdx.x;
    for (int i = gid; i < 73728; i += 96 * 256) zbase[i] = 0.f;
    if (gid < 4608) bar[gid] = 0;   // flags[4096] + slack
    if (blockIdx.x == 0) {
        __shared__ int is64;
        if (threadIdx.x == 0) {
            int a = 1;
            for (int k = 0; k < 32; ++k) if (tgt[2 * k + 1] != 0) a = 0;
            is64 = a;
        }
        __syncthreads();
        int b = threadIdx.x;
        if (b < Bb) {
            int fin = 0;
            tok[0 * Bb + b] = 0;
            for (int s = 1; s < Ss; ++s) {
                int li = b * Tt + s;
                int nt = is64 ? tgt[2 * li] : tgt[li];
                if (nt == EOS_TOK) fin = 1;
                tok[s * Bb + b] = fin ? 0 : nt;
            }
        }
    }
    if (blockIdx.x == 1) {
        __shared__ float sred[256];
        int tid = threadIdx.x;
        sred[tid] = fabsf(vv[tid]) + fabsf(vv[tid + 256]);
        __syncthreads();
        for (int s = 128; s > 0; s >>= 1) {
            if (tid < s) sred[tid] += sred[tid + s];
            __syncthreads();
        }
        if (tid == 0) shiftbuf[0] = sred[0];
    }
}

// S1: gather embeddings for all steps into obuf slot fronts: [t][k][b]
__global__ void k_embx(const float* __restrict__ emb, const int* __restrict__ tok,
                       float* __restrict__ obuf) {
    int i = blockIdx.x * 256 + threadIdx.x;
    if (i < Ss * 8192) {
        int t = i >> 13, e = i & 8191;
        int k = e >> 5, b = e & 31;
        obuf[(size_t)(t + 1) * BD + e] = emb[(size_t)tok[t * 32 + b] * Ee + k];
    }
}

// S2: Wv[b,n,d] = sum_c enc[b,n,c] * W_v[c,d]
__global__ void k_wv(const float* __restrict__ enc, const float* __restrict__ Wv_w,
                     float* __restrict__ Wv) {
    int b = blockIdx.x / 24, nt = blockIdx.x % 24, n0 = nt * 16;
    __shared__ float encL[16 * 512];
    for (int i = 0; i < 32; ++i) {
        int e = threadIdx.x + i * 256;
        int ni = e >> 9, c = e & 511;
        encL[e] = enc[((b * Nn) + (n0 + ni)) * Cc + c];
    }
    __syncthreads();
    int d0 = threadIdx.x, d1 = threadIdx.x + 256;
    float a0[16], a1[16];
#pragma unroll
    for (int i = 0; i < 16; ++i) { a0[i] = 0.f; a1[i] = 0.f; }
    for (int c = 0; c < 512; ++c) {
        float w0 = Wv_w[c * Dd + d0], w1 = Wv_w[c * Dd + d1];
#pragma unroll
        for (int i = 0; i < 16; ++i) {
            float ev = encL[i * 512 + c];
            a0[i] += ev * w0; a1[i] += ev * w1;
        }
    }
#pragma unroll
    for (int i = 0; i < 16; ++i) {
        Wv[((b * Nn) + (n0 + i)) * Dd + d0] = a0[i];
        Wv[((b * Nn) + (n0 + i)) * Dd + d1] = a1[i];
    }
}

// Persistent decode: 256 blocks x 512 threads, weights LDS-resident,
// 4 all-poll barriers per step, 2 of them latency-hidden:
//  - A(t): emb+hx GEMV rows run BEFORE waiting on F(t-1); o_prev rows after.
//  - F(t): hx half runs BEFORE waiting on DE(t); ctx half after.
// Block bid owns output dims {2bid, 2bid+1}. No occupancy cap (r6 lesson:
// a forced VGPR ceiling spills this kernel's ~170 live regs to scratch).
__global__ __launch_bounds__(NTHR) void k_decode(
    const float* __restrict__ enc, const float* __restrict__ W_ih,
    const float* __restrict__ b_ih, const float* __restrict__ W_hh,
    const float* __restrict__ b_hh, const float* __restrict__ W_h,
    const float* __restrict__ vv, const float* __restrict__ W_c,
    const float* __restrict__ b_c, const float* __restrict__ Wv,
    const float* __restrict__ shiftbuf,
    float* __restrict__ hxT, float* __restrict__ xo,
    float* __restrict__ den, float* __restrict__ q, float* __restrict__ ctxT,
    float* __restrict__ obuf, float* __restrict__ alpha_e, int* bar)
{
    __shared__ float Wg[1280 * 8];    // gates cols [k][g*2+dd]    40960B
    __shared__ float Whx[512 * 2];    // W_h cols   [d][dd]         4096B
    __shared__ float Wc[1024 * 2];    // W_c cols   [k][dd]         8192B
    __shared__ float scratch[8192];   // phase-local               32768B
    __shared__ float cxL[64];         // block-private cell state

    int* flags = bar;

    const int tid = threadIdx.x, bid = blockIdx.x;
    const int lane = tid & 63;
    const int d0 = bid * 2;
    const int bp = tid & 15;          // b-pair: b = 2bp, 2bp+1
    const int ab = bid >> 3;          // DE: attention batch
    const int n0 = (bid & 7) * 48;    // DE: n-slice
    const int w  = tid >> 6;          // wave id

    // ---- one-time weight staging into LDS ----
    for (int k = tid; k < 1280; k += NTHR) {
        const float* src = (k < 768) ? (W_ih + (size_t)k * 2048)
                                     : (W_hh + (size_t)(k - 768) * 2048);
#pragma unroll
        for (int g = 0; g < 4; ++g) {
            Wg[k * 8 + g * 2 + 0] = src[g * 512 + d0 + 0];
            Wg[k * 8 + g * 2 + 1] = src[g * 512 + d0 + 1];
        }
    }
    {
        int d = tid;  // NTHR == 512
        Whx[d * 2 + 0] = W_h[(size_t)d * 512 + d0 + 0];
        Whx[d * 2 + 1] = W_h[(size_t)d * 512 + d0 + 1];
    }
    for (int k = tid; k < 1024; k += NTHR) {
        Wc[k * 2 + 0] = W_c[(size_t)k * 512 + d0 + 0];
        Wc[k * 2 + 1] = W_c[(size_t)k * 512 + d0 + 1];
    }
    if (tid < 64) cxL[tid] = 0.f;
    float v8[8];
#pragma unroll
    for (int i = 0; i < 8; ++i) v8[i] = vv[lane * 8 + i];
    float4 wva[6], wvb[6];            // t-invariant Wv fragment (48 floats)
#pragma unroll
    for (int r = 0; r < 6; ++r) {
        const float* wv = Wv + ((size_t)(ab * Nn + n0 + w * 6 + r)) * 512 + lane * 8;
        wva[r] = *(const float4*)wv;
        wvb[r] = *(const float4*)(wv + 4);
    }
    float encR[48];                   // t-invariant enc column slice (48 floats)
#pragma unroll
    for (int i = 0; i < 48; ++i)
        encR[i] = enc[((size_t)(ab * Nn + n0 + i)) * 512 + tid];
    const float SHIFT = shiftbuf[0];
    float bsum0 = 0.f, bsum1 = 0.f, bsum2 = 0.f, bsum3 = 0.f, bcv = 0.f;
    if (tid < 64) {
        int dd = tid >> 5;
        int d = d0 + dd;
        bsum0 = b_ih[0 * 512 + d] + b_hh[0 * 512 + d];
        bsum1 = b_ih[1 * 512 + d] + b_hh[1 * 512 + d];
        bsum2 = b_ih[2 * 512 + d] + b_hh[2 * 512 + d];
        bsum3 = b_ih[3 * 512 + d] + b_hh[3 * 512 + d];
        bcv = b_c[d];
    }
    __syncthreads();

    for (int t = 0; t < Ss; ++t) {
        const int rd = t & 1, wr = 1 - rd;
        const float* hxT_rd = hxT + rd * 16384;
        float*       hxT_wr = hxT + wr * 16384;

        // ---------- Phase A: gates (split: emb+hx pre-wait, o_prev post-wait) ----------
        {
            const float* embx_t = obuf + (size_t)(t + 1) * BD;  // [k][b], k<256
            const float* xo2 = xo - 256 * 32;
            const float* hx2 = hxT_rd - 768 * 32;
            int ks = tid >> 4;           // 32 k-chunks of 40
            int k0 = ks * 40;
            float ax[8], ay[8];
#pragma unroll
            for (int i = 0; i < 8; ++i) { ax[i] = 0.f; ay[i] = 0.f; }
            if (t) {
                // pre-wait: emb (static since k_embx; F(t-1) writes slot t, not t+1)
                //         + hx(t-1) (ready since barrier A(t-1))
#pragma unroll
                for (int kb = 0; kb < 5; ++kb) {
                    int kbase = k0 + kb * 8;
                    if (kbase >= 256 && kbase < 768) continue;   // o rows later
                    const float* base = (kbase < 256) ? embx_t : hx2;
                    float2 xv[8];
#pragma unroll
                    for (int j = 0; j < 8; ++j)
                        xv[j] = ld2_dev(base + (kbase + j) * 32 + 2 * bp);
#pragma unroll
                    for (int j = 0; j < 8; ++j) {
                        int k = kbase + j;
                        float4 wA = *(const float4*)&Wg[k * 8];
                        float4 wB = *(const float4*)&Wg[k * 8 + 4];
                        ax[0] += xv[j].x * wA.x; ay[0] += xv[j].y * wA.x;
                        ax[1] += xv[j].x * wA.y; ay[1] += xv[j].y * wA.y;
                        ax[2] += xv[j].x * wA.z; ay[2] += xv[j].y * wA.z;
                        ax[3] += xv[j].x * wA.w; ay[3] += xv[j].y * wA.w;
                        ax[4] += xv[j].x * wB.x; ay[4] += xv[j].y * wB.x;
                        ax[5] += xv[j].x * wB.y; ay[5] += xv[j].y * wB.y;
                        ax[6] += xv[j].x * wB.z; ay[6] += xv[j].y * wB.z;
                        ax[7] += xv[j].x * wB.w; ay[7] += xv[j].y * wB.w;
                    }
                }
                bar_wait(flags, 4 * t - 1);      // F(t-1) done everywhere
                // post-wait: o_prev rows
#pragma unroll
                for (int kb = 0; kb < 5; ++kb) {
                    int kbase = k0 + kb * 8;
                    if (kbase < 256 || kbase >= 768) continue;
                    float2 xv[8];
#pragma unroll
                    for (int j = 0; j < 8; ++j)
                        xv[j] = ld2_dev(xo2 + (kbase + j) * 32 + 2 * bp);
#pragma unroll
                    for (int j = 0; j < 8; ++j) {
                        int k = kbase + j;
                        float4 wA = *(const float4*)&Wg[k * 8];
                        float4 wB = *(const float4*)&Wg[k * 8 + 4];
                        ax[0] += xv[j].x * wA.x; ay[0] += xv[j].y * wA.x;
                        ax[1] += xv[j].x * wA.y; ay[1] += xv[j].y * wA.y;
                        ax[2] += xv[j].x * wA.z; ay[2] += xv[j].y * wA.z;
                        ax[3] += xv[j].x * wA.w; ay[3] += xv[j].y * wA.w;
                        ax[4] += xv[j].x * wB.x; ay[4] += xv[j].y * wB.x;
                        ax[5] += xv[j].x * wB.y; ay[5] += xv[j].y * wB.y;
                        ax[6] += xv[j].x * wB.z; ay[6] += xv[j].y * wB.z;
                        ax[7] += xv[j].x * wB.w; ay[7] += xv[j].y * wB.w;
                    }
                }
            }
#pragma unroll
            for (int c = 0; c < 8; ++c) {
                scratch[(ks * 8 + c) * 32 + 2 * bp]     = ax[c];
                scratch[(ks * 8 + c) * 32 + 2 * bp + 1] = ay[c];
            }
            __syncthreads();
            if (tid < 256) {
                int col = tid >> 5, b2 = tid & 31;
                float s = 0.f;
#pragma unroll
                for (int k2 = 0; k2 < 32; ++k2) s += scratch[(k2 * 8 + col) * 32 + b2];
                scratch[col * 32 + b2] = s;   // in-place: slot read only by this thread
            }
            __syncthreads();
            if (tid < 64) {
                int dd = tid >> 5, b2 = tid & 31;
                float gi = scratch[(0 * 2 + dd) * 32 + b2] + bsum0;
                float gf = scratch[(1 * 2 + dd) * 32 + b2] + bsum1;
                float gg = scratch[(2 * 2 + dd) * 32 + b2] + bsum2;
                float go = scratch[(3 * 2 + dd) * 32 + b2] + bsum3;
                float c = sigm_(gf) * cxL[tid] + sigm_(gi) * tanh_(gg);
                cxL[tid] = c;
                st_dev(&hxT_wr[(d0 + dd) * 32 + b2], sigm_(go) * tanh_(c));
            }
        }
        bar_arrive(flags, 4 * t);

        // ---------- Phase C: q = hx @ W_h (2 cols) + zero ctxT slice ----------
        bar_wait(flags, 4 * t);
        {
            if (tid < 64)
                st_dev(&ctxT[bid * 64 + tid], 0.f);
            int dc = tid >> 4;            // 32 d-chunks of 16
            int dbase = dc * 16;
            float a00 = 0.f, a01 = 0.f, a10 = 0.f, a11 = 0.f;  // [col][b-in-pair]
#pragma unroll
            for (int db = 0; db < 2; ++db) {
                float2 hv[8];
#pragma unroll
                for (int j = 0; j < 8; ++j)
                    hv[j] = ld2_dev(hxT_wr + (dbase + db * 8 + j) * 32 + 2 * bp);
#pragma unroll
                for (int j = 0; j < 8; ++j) {
                    int d = dbase + db * 8 + j;
                    float w0 = Whx[d * 2 + 0], w1 = Whx[d * 2 + 1];
                    a00 += hv[j].x * w0; a10 += hv[j].y * w0;
                    a01 += hv[j].x * w1; a11 += hv[j].y * w1;
                }
            }
            scratch[(dc * 2 + 0) * 32 + 2 * bp]     = a00;
            scratch[(dc * 2 + 0) * 32 + 2 * bp + 1] = a10;
            scratch[(dc * 2 + 1) * 32 + 2 * bp]     = a01;
            scratch[(dc * 2 + 1) * 32 + 2 * bp + 1] = a11;
            __syncthreads();
            if (tid < 64) {
                int jj = tid >> 5, b2 = tid & 31;
                float s = 0.f;
#pragma unroll
                for (int d2 = 0; d2 < 32; ++d2) s += scratch[(d2 * 2 + jj) * 32 + b2];
                st_dev(&q[b2 * 512 + d0 + jj], s);
            }
        }
        bar_arrive(flags, 4 * t + 1);

        // ---------- Phase DE: scores + exp(shifted) + ctx atomics ----------
        bar_wait(flags, 4 * t + 1);
        {
            float* esc = scratch;            // 48 e-values
            float q8[8];
#pragma unroll
            for (int j = 0; j < 4; ++j) {    // 4 batched sc1 float2 loads
                float2 qv = ld2_dev(&q[ab * 512 + lane * 8 + 2 * j]);
                q8[2 * j] = qv.x; q8[2 * j + 1] = qv.y;
            }
#pragma unroll
            for (int r = 0; r < 6; ++r) {
                float s = v8[0] * tanh_(q8[0] + wva[r].x) + v8[1] * tanh_(q8[1] + wva[r].y)
                        + v8[2] * tanh_(q8[2] + wva[r].z) + v8[3] * tanh_(q8[3] + wva[r].w)
                        + v8[4] * tanh_(q8[4] + wvb[r].x) + v8[5] * tanh_(q8[5] + wvb[r].y)
                        + v8[6] * tanh_(q8[6] + wvb[r].z) + v8[7] * tanh_(q8[7] + wvb[r].w);
#pragma unroll
                for (int off = 32; off > 0; off >>= 1)
                    s += __shfl_down(s, off, 64);
                if (lane == 0) esc[w * 6 + r] = __expf(s - SHIFT);
            }
            __syncthreads();
            if (tid < 48)
                alpha_e[((size_t)ab * Ss + t) * Nn + n0 + tid] = esc[tid];
            if (tid == 0) {
                float sd = 0.f;
                for (int i = 0; i < 48; ++i) sd += esc[i];
                atomicAdd(&den[t * 32 + ab], sd);
            }
            float acc = 0.f;
#pragma unroll 8
            for (int i = 0; i < 48; ++i)
                acc += esc[i] * encR[i];     // enc slice from registers
            atomicAdd(&ctxT[tid * 32 + ab], acc);
        }
        bar_arrive(flags, 4 * t + 2);

        // ---------- Phase F: o_t (split: hx half pre-wait, ctx half post-wait) ----------
        {
            int kc = tid >> 4;            // 32 k-chunks of 32 (16 hx + 16 ctx)
            int kb0 = kc * 32;
            float a00 = 0.f, a01 = 0.f, a10 = 0.f, a11 = 0.f;
            if (kc < 16) {                // hx half (ready since barrier A(t))
#pragma unroll
                for (int kb = 0; kb < 4; ++kb) {
                    float2 xv[8];
#pragma unroll
                    for (int j = 0; j < 8; ++j)
                        xv[j] = ld2_dev(hxT_wr + (kb0 + kb * 8 + j) * 32 + 2 * bp);
#pragma unroll
                    for (int j = 0; j < 8; ++j) {
                        int k = kb0 + kb * 8 + j;
                        float w0 = Wc[k * 2 + 0], w1 = Wc[k * 2 + 1];
                        a00 += xv[j].x * w0; a10 += xv[j].y * w0;
                        a01 += xv[j].x * w1; a11 += xv[j].y * w1;
                    }
                }
            }
            bar_wait(flags, 4 * t + 2);       // DE done: ctx/den ready
            if (kc >= 16) {
                const float* src = ctxT - 512 * 32;
                float2 dp = ld2_dev(&den[t * 32 + 2 * bp]);
                float dx = 1.0f / dp.x, dy = 1.0f / dp.y;
#pragma unroll
                for (int kb = 0; kb < 4; ++kb) {
                    float2 xv[8];
#pragma unroll
                    for (int j = 0; j < 8; ++j)
                        xv[j] = ld2_dev(src + (kb0 + kb * 8 + j) * 32 + 2 * bp);
#pragma unroll
                    for (int j = 0; j < 8; ++j) {
                        int k = kb0 + kb * 8 + j;
                        float w0 = Wc[k * 2 + 0], w1 = Wc[k * 2 + 1];
                        a00 += xv[j].x * w0; a10 += xv[j].y * w0;
                        a01 += xv[j].x * w1; a11 += xv[j].y * w1;
                    }
                }
                a00 *= dx; a01 *= dx; a10 *= dy; a11 *= dy;
            }
            scratch[(kc * 2 + 0) * 32 + 2 * bp]     = a00;
            scratch[(kc * 2 + 0) * 32 + 2 * bp + 1] = a10;
            scratch[(kc * 2 + 1) * 32 + 2 * bp]     = a01;
            scratch[(kc * 2 + 1) * 32 + 2 * bp + 1] = a11;
            __syncthreads();
            if (tid < 64) {
                int dd = tid >> 5, b2 = tid & 31;
                float s = bcv;
#pragma unroll
                for (int k2 = 0; k2 < 32; ++k2) s += scratch[(k2 * 2 + dd) * 32 + b2];
                float o = tanh_(s);
                st_dev(&xo[(d0 + dd) * 32 + b2], o);
                obuf[(size_t)(t + 1) * BD + b2 * 512 + d0 + dd] = o;  // read post-kernel
            }
        }
        bar_arrive(flags, 4 * t + 3);
    }
}

// Deferred logits GEMM.
__global__ void k_logits(const float* __restrict__ obuf, const float* __restrict__ W_out,
                         const float* __restrict__ b_out, float* __restrict__ out_logits) {
    int b = blockIdx.x / 24, tt = blockIdx.x % 24;
    int t0 = tt * 8;
    int tmax = min(8, Ss - t0);
    __shared__ float oL[8 * 512];
    int tid = threadIdx.x;
    for (int i = 0; i < 16; ++i) {
        int e = tid + i * 256;
        int ti = e >> 9, d = e & 511;
        oL[e] = (ti < tmax) ? obuf[(size_t)(t0 + ti + 1) * BD + b * Dd + d] : 0.f;
    }
    __syncthreads();
    int v0 = tid, v1 = tid + 256, v2 = tid + 512;
    bool h2 = (v2 < Vv);
    int v2c = h2 ? v2 : 0;
    float acc[3][8];
#pragma unroll
    for (int s = 0; s < 3; ++s)
#pragma unroll
        for (int ti = 0; ti < 8; ++ti) acc[s][ti] = 0.f;
    for (int d = 0; d < 512; ++d) {
        float w0 = W_out[d * Vv + v0];
        float w1 = W_out[d * Vv + v1];
        float w2 = W_out[d * Vv + v2c];
#pragma unroll
        for (int ti = 0; ti < 8; ++ti) {
            float o = oL[ti * 512 + d];
            acc[0][ti] += o * w0; acc[1][ti] += o * w1; acc[2][ti] += o * w2;
        }
    }
    for (int ti = 0; ti < tmax; ++ti) {
        size_t base = (size_t)b * (Ss * Vv) + (size_t)(t0 + ti) * Vv;
        out_logits[base + v0] = acc[0][ti] + b_out[v0];
        out_logits[base + v1] = acc[1][ti] + b_out[v1];
        if (h2) out_logits[base + v2] = acc[2][ti] + b_out[v2];
    }
}

// Normalize alphas: alpha /= denom[b,t]
__global__ void k_anorm(float* __restrict__ alph, const float* __restrict__ den) {
    int i = blockIdx.x * 256 + threadIdx.x;
    if (i < ALPHA_SZ) {
        int bt = i / Nn;
        int t = bt % Ss, b = bt / Ss;
        alph[i] = alph[i] / den[t * 32 + b];
    }
}

extern "C" void kernel_launch(void* const* d_in, const int* in_sizes, int n_in,
                              void* d_out, int out_size, void* d_ws, size_t ws_size,
                              hipStream_t stream) {
    const float* enc   = (const float*)d_in[0];
    const int*   tgt   = (const int*)d_in[1];
    const float* emb   = (const float*)d_in[2];
    const float* W_ih  = (const float*)d_in[3];
    const float* b_ih  = (const float*)d_in[4];
    const float* W_hh  = (const float*)d_in[5];
    const float* b_hh  = (const float*)d_in[6];
    const float* W_h   = (const float*)d_in[7];
    const float* W_v   = (const float*)d_in[8];
    const float* vv    = (const float*)d_in[9];
    const float* W_c   = (const float*)d_in[10];
    const float* b_c   = (const float*)d_in[11];
    const float* W_out = (const float*)d_in[12];
    const float* b_out = (const float*)d_in[13];

    float* wsf   = (float*)d_ws;
    int*   tok   = (int*)d_ws;
    float* shiftb= wsf + OFF_SHIFT;
    float* Wv    = wsf + OFF_WV;
    float* hxT   = wsf + OFF_HXT;
    float* xo    = wsf + OFF_XO;
    float* den   = wsf + OFF_DEN;
    float* q     = wsf + OFF_Q;
    float* ctxT  = wsf + OFF_CTX;
    float* obuf  = wsf + OFF_OBUF;
    int*   bar   = (int*)(wsf + OFF_BAR);

    float* out_logits = (float*)d_out;
    float* out_alphas = (float*)d_out + LOGITS_SZ;

    k_setup<<<96, 256, 0, stream>>>(tgt, vv, hxT, bar, tok, shiftb);
    k_embx<<<(Ss * 8192 + 255) / 256, 256, 0, stream>>>(emb, tok, obuf);
    k_wv<<<768, 256, 0, stream>>>(enc, W_v, Wv);
    k_decode<<<NBLK, NTHR, 0, stream>>>(enc, W_ih, b_ih, W_hh, b_hh, W_h, vv,
                                        W_c, b_c, Wv, shiftb,
                                        hxT, xo, den, q, ctxT, obuf,
                                        out_alphas, bar);
    k_logits<<<768, 256, 0, stream>>>(obuf, W_out, b_out, out_logits);
    k_anorm<<<(ALPHA_SZ + 255) / 256, 256, 0, stream>>>(out_alphas, den);
}

// Round 8
// 8285.487 us; speedup vs baseline: 2.1626x; 1.1183x over previous
//
#include <hip/hip_runtime.h>
#include <cstdint>

#define Bb 32
#define Cc 512
#define Nn 384
#define Vv 600
#define Ee 256
#define Dd 512
#define Tt 192
#define Ss 191
#define EOS_TOK 130
#define BD (Bb*Dd)          // 16384
#define NBLK 256
#define NTHR 512

// ---- ws layout (float offsets) ----  (r0/r3 proven layout; hxB reuses OFF_CX)
#define OFF_TOK   0                      // int tok[Ss*Bb]
#define OFF_SHIFT 8192                   // float shift[1]
#define OFF_WV    8256                   // Bb*Nn*Dd = 6291456
#define OFF_HXT   (OFF_WV + 6291456)     // 2 * 512*32 (double-buffered, [d][b])
#define OFF_XO    (OFF_HXT + 32768)      // 512*32 o_prev transposed [d][b]
#define OFF_CX    (OFF_XO + 16384)       // hxB[b][d] 32*512 (A writes, C reads)
#define OFF_DEN   (OFF_CX + 16384)       // denom[t][b] 191*32 (pad 8192)
#define OFF_Q     (OFF_DEN + 8192)       // q[b][d] 32*512
#define OFF_CTX   (OFF_Q + 16384)        // ctxT[c][b] 512*32
#define OFF_OBUF  (OFF_CTX + 16384)      // 192*BD; slot t+1 front 8192 doubles as embx[t]
#define OFF_BAR   (OFF_OBUF + 192*16384) // flags[256*16] + genv[32*16] + qdone[32*16]

#define LOGITS_SZ (Bb*Ss*Vv)  // 3667200
#define ALPHA_SZ  (Bb*Ss*Nn)  // 2347008

__device__ __forceinline__ float sigm_(float x) {
    float e = __expf(-x);
    return __builtin_amdgcn_rcpf(1.0f + e);
}
__device__ __forceinline__ float tanh_(float x) {
    float xc = fminf(15.0f, fmaxf(-15.0f, x));
    float e = __expf(2.0f * xc);
    return (e - 1.0f) * __builtin_amdgcn_rcpf(e + 1.0f);
}

// Write-through device store (sc1): at LLC once vmcnt retires; __syncthreads
// drains vmcnt, so no release fence is ever needed.
__device__ __forceinline__ void st_dev(float* p, float v) {
    __hip_atomic_store(p, v, __ATOMIC_RELAXED, __HIP_MEMORY_SCOPE_AGENT);
}
__device__ __forceinline__ float ld1_dev(const float* p) {
    return __hip_atomic_load(p, __ATOMIC_RELAXED, __HIP_MEMORY_SCOPE_AGENT);
}
// 8-byte coherent load (sc1 bypass, relaxed).
__device__ __forceinline__ float2 ld2_dev(const float* p) {
    unsigned long long u = __hip_atomic_load((const unsigned long long*)p,
                                             __ATOMIC_RELAXED,
                                             __HIP_MEMORY_SCOPE_AGENT);
    float2 f;
    f.x = __uint_as_float((unsigned int)u);
    f.y = __uint_as_float((unsigned int)(u >> 32));
    return f;
}

// Flag-array device barrier (r3's proven aggregator protocol, unchanged):
// arrival = one independent sc1 store per block; block 0 wave 0 polls all 256
// flags (4/lane) and releases 32 replicated gen lines (64B apart).
__device__ __forceinline__ void gbar(int* flags, int* genv, int ibar) {
    __syncthreads();   // drains vmcnt: all sc1 data stores ack'd at LLC
    const int target = ibar + 1;
    if (threadIdx.x == 0)
        __hip_atomic_store(&flags[blockIdx.x * 16], target, __ATOMIC_RELAXED,
                           __HIP_MEMORY_SCOPE_AGENT);
    if (blockIdx.x == 0) {
        if (threadIdx.x < 64) {
            int l = threadIdx.x * 4;
            for (;;) {
                int f0 = __hip_atomic_load(&flags[(l + 0) * 16], __ATOMIC_RELAXED,
                                           __HIP_MEMORY_SCOPE_AGENT);
                int f1 = __hip_atomic_load(&flags[(l + 1) * 16], __ATOMIC_RELAXED,
                                           __HIP_MEMORY_SCOPE_AGENT);
                int f2 = __hip_atomic_load(&flags[(l + 2) * 16], __ATOMIC_RELAXED,
                                           __HIP_MEMORY_SCOPE_AGENT);
                int f3 = __hip_atomic_load(&flags[(l + 3) * 16], __ATOMIC_RELAXED,
                                           __HIP_MEMORY_SCOPE_AGENT);
                if (__all(f0 >= target && f1 >= target &&
                          f2 >= target && f3 >= target)) break;
                __builtin_amdgcn_s_sleep(1);
            }
            if (threadIdx.x < 32)
                __hip_atomic_store(&genv[threadIdx.x * 16], target,
                                   __ATOMIC_RELAXED, __HIP_MEMORY_SCOPE_AGENT);
        }
    } else if (threadIdx.x == 0) {
        int* g = &genv[(blockIdx.x >> 3) * 16];
        while (__hip_atomic_load(g, __ATOMIC_RELAXED,
                                 __HIP_MEMORY_SCOPE_AGENT) < target)
            __builtin_amdgcn_s_sleep(2);
    }
    __syncthreads();
}

// S0: zero state/flags/denoms, token sequence, exp-shift = sum|v|.
__global__ void k_setup(const int* __restrict__ tgt, const float* __restrict__ vv,
                        float* zbase, int* bar, int* tok, float* shiftbuf) {
    int gid = blockIdx.x * 256 + threadIdx.x;
    for (int i = gid; i < 73728; i += 96 * 256) zbase[i] = 0.f;
    if (gid < 5120) bar[gid] = 0;   // flags[4096] + genv[512] + qdone[512]
    if (blockIdx.x == 0) {
        __shared__ int is64;
        if (threadIdx.x == 0) {
            int a = 1;
            for (int k = 0; k < 32; ++k) if (tgt[2 * k + 1] != 0) a = 0;
            is64 = a;
        }
        __syncthreads();
        int b = threadIdx.x;
        if (b < Bb) {
            int fin = 0;
            tok[0 * Bb + b] = 0;
            for (int s = 1; s < Ss; ++s) {
                int li = b * Tt + s;
                int nt = is64 ? tgt[2 * li] : tgt[li];
                if (nt == EOS_TOK) fin = 1;
                tok[s * Bb + b] = fin ? 0 : nt;
            }
        }
    }
    if (blockIdx.x == 1) {
        __shared__ float sred[256];
        int tid = threadIdx.x;
        sred[tid] = fabsf(vv[tid]) + fabsf(vv[tid + 256]);
        __syncthreads();
        for (int s = 128; s > 0; s >>= 1) {
            if (tid < s) sred[tid] += sred[tid + s];
            __syncthreads();
        }
        if (tid == 0) shiftbuf[0] = sred[0];
    }
}

// S1: gather embeddings for all steps into obuf slot fronts: [t][k][b]
__global__ void k_embx(const float* __restrict__ emb, const int* __restrict__ tok,
                       float* __restrict__ obuf) {
    int i = blockIdx.x * 256 + threadIdx.x;
    if (i < Ss * 8192) {
        int t = i >> 13, e = i & 8191;
        int k = e >> 5, b = e & 31;
        obuf[(size_t)(t + 1) * BD + e] = emb[(size_t)tok[t * 32 + b] * Ee + k];
    }
}

// S2: Wv[b,n,d] = sum_c enc[b,n,c] * W_v[c,d]
__global__ void k_wv(const float* __restrict__ enc, const float* __restrict__ Wv_w,
                     float* __restrict__ Wv) {
    int b = blockIdx.x / 24, nt = blockIdx.x % 24, n0 = nt * 16;
    __shared__ float encL[16 * 512];
    for (int i = 0; i < 32; ++i) {
        int e = threadIdx.x + i * 256;
        int ni = e >> 9, c = e & 511;
        encL[e] = enc[((b * Nn) + (n0 + ni)) * Cc + c];
    }
    __syncthreads();
    int d0 = threadIdx.x, d1 = threadIdx.x + 256;
    float a0[16], a1[16];
#pragma unroll
    for (int i = 0; i < 16; ++i) { a0[i] = 0.f; a1[i] = 0.f; }
    for (int c = 0; c < 512; ++c) {
        float w0 = Wv_w[c * Dd + d0], w1 = Wv_w[c * Dd + d1];
#pragma unroll
        for (int i = 0; i < 16; ++i) {
            float ev = encL[i * 512 + c];
            a0[i] += ev * w0; a1[i] += ev * w1;
        }
    }
#pragma unroll
    for (int i = 0; i < 16; ++i) {
        Wv[((b * Nn) + (n0 + i)) * Dd + d0] = a0[i];
        Wv[((b * Nn) + (n0 + i)) * Dd + d1] = a1[i];
    }
}

// Persistent decode: 256 blocks x 512 threads, weights LDS-resident,
// 3 global barriers per step + 1 fine-grained producer flag:
//   A -> gbar -> { C on blocks 0..31 (q[b] via L2-resident W_h) ; posts
//   qdone[b] } -> DE blocks poll their batch's flag -> DE -> gbar -> F -> gbar
// q(t) for batch b is consumed only by the 8 DE blocks with ab==b, so the
// global C-barrier of r3 is replaced by one sc1 flag line (8 readers).
__global__ __launch_bounds__(NTHR) void k_decode(
    const float* __restrict__ enc, const float* __restrict__ W_ih,
    const float* __restrict__ b_ih, const float* __restrict__ W_hh,
    const float* __restrict__ b_hh, const float* __restrict__ W_h,
    const float* __restrict__ vv, const float* __restrict__ W_c,
    const float* __restrict__ b_c, const float* __restrict__ Wv,
    const float* __restrict__ shiftbuf,
    float* __restrict__ hxT, float* __restrict__ xo, float* __restrict__ hxB,
    float* __restrict__ den, float* __restrict__ q, float* __restrict__ ctxT,
    float* __restrict__ obuf, float* __restrict__ alpha_e, int* bar)
{
    __shared__ float Wg[1280 * 8];    // gates cols [k][g*2+dd]    40960B
    __shared__ float Wc[1024 * 2];    // W_c cols   [k][dd]         8192B
    __shared__ float scratch[8192];   // phase-local               32768B
    __shared__ float hxLs[512];       // C: staged hx row           2048B
    __shared__ float cxL[64];         // block-private cell state

    int* flags = bar;
    int* genv  = bar + 4096;
    int* qdone = bar + 4608;

    const int tid = threadIdx.x, bid = blockIdx.x;
    const int lane = tid & 63;
    const int d0 = bid * 2;
    const int bp = tid & 15;          // b-pair: b = 2bp, 2bp+1
    const int ab = bid >> 3;          // DE: attention batch
    const int n0 = (bid & 7) * 48;    // DE: n-slice
    const int w  = tid >> 6;          // wave id

    // ---- one-time weight staging into LDS ----
    for (int k = tid; k < 1280; k += NTHR) {
        const float* src = (k < 768) ? (W_ih + (size_t)k * 2048)
                                     : (W_hh + (size_t)(k - 768) * 2048);
#pragma unroll
        for (int g = 0; g < 4; ++g) {
            Wg[k * 8 + g * 2 + 0] = src[g * 512 + d0 + 0];
            Wg[k * 8 + g * 2 + 1] = src[g * 512 + d0 + 1];
        }
    }
    for (int k = tid; k < 1024; k += NTHR) {
        Wc[k * 2 + 0] = W_c[(size_t)k * 512 + d0 + 0];
        Wc[k * 2 + 1] = W_c[(size_t)k * 512 + d0 + 1];
    }
    if (tid < 64) cxL[tid] = 0.f;
    float v8[8];
#pragma unroll
    for (int i = 0; i < 8; ++i) v8[i] = vv[lane * 8 + i];
    float4 wva[6], wvb[6];            // t-invariant Wv fragment (48 floats)
#pragma unroll
    for (int r = 0; r < 6; ++r) {
        const float* wv = Wv + ((size_t)(ab * Nn + n0 + w * 6 + r)) * 512 + lane * 8;
        wva[r] = *(const float4*)wv;
        wvb[r] = *(const float4*)(wv + 4);
    }
    float encR[48];                   // t-invariant enc column slice (48 floats)
#pragma unroll
    for (int i = 0; i < 48; ++i)
        encR[i] = enc[((size_t)(ab * Nn + n0 + i)) * 512 + tid];
    const float SHIFT = shiftbuf[0];
    float bsum0 = 0.f, bsum1 = 0.f, bsum2 = 0.f, bsum3 = 0.f, bcv = 0.f;
    if (tid < 64) {
        int dd = tid >> 5;
        int d = d0 + dd;
        bsum0 = b_ih[0 * 512 + d] + b_hh[0 * 512 + d];
        bsum1 = b_ih[1 * 512 + d] + b_hh[1 * 512 + d];
        bsum2 = b_ih[2 * 512 + d] + b_hh[2 * 512 + d];
        bsum3 = b_ih[3 * 512 + d] + b_hh[3 * 512 + d];
        bcv = b_c[d];
    }
    __syncthreads();

    int ib = 0;
    for (int t = 0; t < Ss; ++t) {
        const int rd = t & 1, wr = 1 - rd;
        const float* hxT_rd = hxT + rd * 16384;
        float*       hxT_wr = hxT + wr * 16384;

        // ---------- Phase A: gates (full K) + LSTM + ctx-zero ----------
        {
            // zero this block's ctxT slice for THIS step's DE atomics
            // (safe: A(t) runs strictly after F(t-1)'s gbar, which follows
            //  F's ctxT reads; at t=0 this provides the initial zeroing)
            if (tid < 64)
                st_dev(&ctxT[bid * 64 + tid], 0.f);
            const float* embx_t = obuf + (size_t)(t + 1) * BD;  // [k][b], k<256
            const float* xo2 = xo - 256 * 32;
            const float* hx2 = hxT_rd - 768 * 32;
            int ks = tid >> 4;           // 32 k-chunks of 40
            int k0 = ks * 40;
            float ax[8], ay[8];
#pragma unroll
            for (int i = 0; i < 8; ++i) { ax[i] = 0.f; ay[i] = 0.f; }
            if (t) {
#pragma unroll
                for (int kb = 0; kb < 5; ++kb) {
                    int kbase = k0 + kb * 8;
                    float2 xv[8];
#pragma unroll
                    for (int j = 0; j < 8; ++j) {      // batch: 8 outstanding sc1 loads
                        int k = kbase + j;
                        const float* base = (k < 256) ? embx_t : ((k < 768) ? xo2 : hx2);
                        xv[j] = ld2_dev(base + k * 32 + 2 * bp);
                    }
#pragma unroll
                    for (int j = 0; j < 8; ++j) {      // then use
                        int k = kbase + j;
                        float4 wA = *(const float4*)&Wg[k * 8];
                        float4 wB = *(const float4*)&Wg[k * 8 + 4];
                        ax[0] += xv[j].x * wA.x; ay[0] += xv[j].y * wA.x;
                        ax[1] += xv[j].x * wA.y; ay[1] += xv[j].y * wA.y;
                        ax[2] += xv[j].x * wA.z; ay[2] += xv[j].y * wA.z;
                        ax[3] += xv[j].x * wA.w; ay[3] += xv[j].y * wA.w;
                        ax[4] += xv[j].x * wB.x; ay[4] += xv[j].y * wB.x;
                        ax[5] += xv[j].x * wB.y; ay[5] += xv[j].y * wB.y;
                        ax[6] += xv[j].x * wB.z; ay[6] += xv[j].y * wB.z;
                        ax[7] += xv[j].x * wB.w; ay[7] += xv[j].y * wB.w;
                    }
                }
            }
#pragma unroll
            for (int c = 0; c < 8; ++c) {
                scratch[(ks * 8 + c) * 32 + 2 * bp]     = ax[c];
                scratch[(ks * 8 + c) * 32 + 2 * bp + 1] = ay[c];
            }
            __syncthreads();
            if (tid < 256) {
                int col = tid >> 5, b2 = tid & 31;
                float s = 0.f;
#pragma unroll
                for (int k2 = 0; k2 < 32; ++k2) s += scratch[(k2 * 8 + col) * 32 + b2];
                scratch[col * 32 + b2] = s;   // in-place: slot read only by this thread
            }
            __syncthreads();
            if (tid < 64) {
                int dd = tid >> 5, b2 = tid & 31;
                float gi = scratch[(0 * 2 + dd) * 32 + b2] + bsum0;
                float gf = scratch[(1 * 2 + dd) * 32 + b2] + bsum1;
                float gg = scratch[(2 * 2 + dd) * 32 + b2] + bsum2;
                float go = scratch[(3 * 2 + dd) * 32 + b2] + bsum3;
                float c = sigm_(gf) * cxL[tid] + sigm_(gi) * tanh_(gg);
                cxL[tid] = c;
                float h = sigm_(go) * tanh_(c);
                st_dev(&hxT_wr[(d0 + dd) * 32 + b2], h);
                st_dev(&hxB[b2 * 512 + d0 + dd], h);   // row-major copy for C
            }
        }
        gbar(flags, genv, ib++);

        // ---------- Phase C (blocks 0..31 only): q[b][:] = hx[b] @ W_h ----------
        // W_h is t-invariant + plain-loaded -> L2-resident (all other phases
        // bypass L2 via sc1, so nothing evicts it). Producer posts qdone[b].
        if (bid < 32) {
            const int b = bid;
            hxLs[tid] = ld1_dev(&hxB[b * 512 + tid]);
            __syncthreads();
            float q0 = 0.f, q1 = 0.f, q2 = 0.f, q3 = 0.f;
            float q4 = 0.f, q5 = 0.f, q6 = 0.f, q7 = 0.f;
            for (int d2 = 0; d2 < 512; d2 += 8) {
                q0 += hxLs[d2 + 0] * W_h[(size_t)(d2 + 0) * 512 + tid];
                q1 += hxLs[d2 + 1] * W_h[(size_t)(d2 + 1) * 512 + tid];
                q2 += hxLs[d2 + 2] * W_h[(size_t)(d2 + 2) * 512 + tid];
                q3 += hxLs[d2 + 3] * W_h[(size_t)(d2 + 3) * 512 + tid];
                q4 += hxLs[d2 + 4] * W_h[(size_t)(d2 + 4) * 512 + tid];
                q5 += hxLs[d2 + 5] * W_h[(size_t)(d2 + 5) * 512 + tid];
                q6 += hxLs[d2 + 6] * W_h[(size_t)(d2 + 6) * 512 + tid];
                q7 += hxLs[d2 + 7] * W_h[(size_t)(d2 + 7) * 512 + tid];
            }
            st_dev(&q[b * 512 + tid],
                   ((q0 + q1) + (q2 + q3)) + ((q4 + q5) + (q6 + q7)));
            __syncthreads();   // drain vmcnt: q stores ack'd at LLC
            if (tid == 0)
                __hip_atomic_store(&qdone[b * 16], t + 1, __ATOMIC_RELAXED,
                                   __HIP_MEMORY_SCOPE_AGENT);
        }

        // ---------- Phase DE: poll q-ready, then scores + exp + ctx atomics ----------
        {
            if (tid == 0) {
                int* g = &qdone[ab * 16];
                while (__hip_atomic_load(g, __ATOMIC_RELAXED,
                                         __HIP_MEMORY_SCOPE_AGENT) < t + 1)
                    __builtin_amdgcn_s_sleep(1);
            }
            __syncthreads();
            float* esc = scratch;            // 48 e-values
            float q8[8];
#pragma unroll
            for (int j = 0; j < 4; ++j) {    // 4 batched sc1 float2 loads
                float2 qv = ld2_dev(&q[ab * 512 + lane * 8 + 2 * j]);
                q8[2 * j] = qv.x; q8[2 * j + 1] = qv.y;
            }
#pragma unroll
            for (int r = 0; r < 6; ++r) {
                float s = v8[0] * tanh_(q8[0] + wva[r].x) + v8[1] * tanh_(q8[1] + wva[r].y)
                        + v8[2] * tanh_(q8[2] + wva[r].z) + v8[3] * tanh_(q8[3] + wva[r].w)
                        + v8[4] * tanh_(q8[4] + wvb[r].x) + v8[5] * tanh_(q8[5] + wvb[r].y)
                        + v8[6] * tanh_(q8[6] + wvb[r].z) + v8[7] * tanh_(q8[7] + wvb[r].w);
#pragma unroll
                for (int off = 32; off > 0; off >>= 1)
                    s += __shfl_down(s, off, 64);
                if (lane == 0) esc[w * 6 + r] = __expf(s - SHIFT);
            }
            __syncthreads();
            if (tid < 48)
                alpha_e[((size_t)ab * Ss + t) * Nn + n0 + tid] = esc[tid];
            if (tid == 0) {
                float sd = 0.f;
                for (int i = 0; i < 48; ++i) sd += esc[i];
                atomicAdd(&den[t * 32 + ab], sd);
            }
            float acc = 0.f;
#pragma unroll 8
            for (int i = 0; i < 48; ++i)
                acc += esc[i] * encR[i];     // enc slice from registers
            atomicAdd(&ctxT[tid * 32 + ab], acc);
        }
        gbar(flags, genv, ib++);

        // ---------- Phase F: o_t = tanh([hx|ctx/den] @ W_c + b_c) (2 cols) ----------
        {
            int kc = tid >> 4;            // 32 k-chunks of 32 (16 hx + 16 ctx)
            float2 dp = ld2_dev(&den[t * 32 + 2 * bp]);
            float dx = 1.0f / dp.x, dy = 1.0f / dp.y;
            const float* src = (kc < 16) ? hxT_wr : (ctxT - 512 * 32);
            int kb0 = kc * 32;
            float a00 = 0.f, a01 = 0.f, a10 = 0.f, a11 = 0.f;
#pragma unroll
            for (int kb = 0; kb < 4; ++kb) {
                float2 xv[8];
#pragma unroll
                for (int j = 0; j < 8; ++j)
                    xv[j] = ld2_dev(src + (kb0 + kb * 8 + j) * 32 + 2 * bp);
#pragma unroll
                for (int j = 0; j < 8; ++j) {
                    int k = kb0 + kb * 8 + j;
                    float w0 = Wc[k * 2 + 0], w1 = Wc[k * 2 + 1];
                    a00 += xv[j].x * w0; a10 += xv[j].y * w0;
                    a01 += xv[j].x * w1; a11 += xv[j].y * w1;
                }
            }
            if (kc >= 16) { a00 *= dx; a01 *= dx; a10 *= dy; a11 *= dy; }
            scratch[(kc * 2 + 0) * 32 + 2 * bp]     = a00;
            scratch[(kc * 2 + 0) * 32 + 2 * bp + 1] = a10;
            scratch[(kc * 2 + 1) * 32 + 2 * bp]     = a01;
            scratch[(kc * 2 + 1) * 32 + 2 * bp + 1] = a11;
            __syncthreads();
            if (tid < 64) {
                int dd = tid >> 5, b2 = tid & 31;
                float s = bcv;
#pragma unroll
                for (int k2 = 0; k2 < 32; ++k2) s += scratch[(k2 * 2 + dd) * 32 + b2];
                float o = tanh_(s);
                st_dev(&xo[(d0 + dd) * 32 + b2], o);
                obuf[(size_t)(t + 1) * BD + b2 * 512 + d0 + dd] = o;  // read post-kernel
            }
        }
        gbar(flags, genv, ib++);
    }
}

// Deferred logits GEMM.
__global__ void k_logits(const float* __restrict__ obuf, const float* __restrict__ W_out,
                         const float* __restrict__ b_out, float* __restrict__ out_logits) {
    int b = blockIdx.x / 24, tt = blockIdx.x % 24;
    int t0 = tt * 8;
    int tmax = min(8, Ss - t0);
    __shared__ float oL[8 * 512];
    int tid = threadIdx.x;
    for (int i = 0; i < 16; ++i) {
        int e = tid + i * 256;
        int ti = e >> 9, d = e & 511;
        oL[e] = (ti < tmax) ? obuf[(size_t)(t0 + ti + 1) * BD + b * Dd + d] : 0.f;
    }
    __syncthreads();
    int v0 = tid, v1 = tid + 256, v2 = tid + 512;
    bool h2 = (v2 < Vv);
    int v2c = h2 ? v2 : 0;
    float acc[3][8];
#pragma unroll
    for (int s = 0; s < 3; ++s)
#pragma unroll
        for (int ti = 0; ti < 8; ++ti) acc[s][ti] = 0.f;
    for (int d = 0; d < 512; ++d) {
        float w0 = W_out[d * Vv + v0];
        float w1 = W_out[d * Vv + v1];
        float w2 = W_out[d * Vv + v2c];
#pragma unroll
        for (int ti = 0; ti < 8; ++ti) {
            float o = oL[ti * 512 + d];
            acc[0][ti] += o * w0; acc[1][ti] += o * w1; acc[2][ti] += o * w2;
        }
    }
    for (int ti = 0; ti < tmax; ++ti) {
        size_t base = (size_t)b * (Ss * Vv) + (size_t)(t0 + ti) * Vv;
        out_logits[base + v0] = acc[0][ti] + b_out[v0];
        out_logits[base + v1] = acc[1][ti] + b_out[v1];
        if (h2) out_logits[base + v2] = acc[2][ti] + b_out[v2];
    }
}

// Normalize alphas: alpha /= denom[b,t]
__global__ void k_anorm(float* __restrict__ alph, const float* __restrict__ den) {
    int i = blockIdx.x * 256 + threadIdx.x;
    if (i < ALPHA_SZ) {
        int bt = i / Nn;
        int t = bt % Ss, b = bt / Ss;
        alph[i] = alph[i] / den[t * 32 + b];
    }
}

extern "C" void kernel_launch(void* const* d_in, const int* in_sizes, int n_in,
                              void* d_out, int out_size, void* d_ws, size_t ws_size,
                              hipStream_t stream) {
    const float* enc   = (const float*)d_in[0];
    const int*   tgt   = (const int*)d_in[1];
    const float* emb   = (const float*)d_in[2];
    const float* W_ih  = (const float*)d_in[3];
    const float* b_ih  = (const float*)d_in[4];
    const float* W_hh  = (const float*)d_in[5];
    const float* b_hh  = (const float*)d_in[6];
    const float* W_h   = (const float*)d_in[7];
    const float* W_v   = (const float*)d_in[8];
    const float* vv    = (const float*)d_in[9];
    const float* W_c   = (const float*)d_in[10];
    const float* b_c   = (const float*)d_in[11];
    const float* W_out = (const float*)d_in[12];
    const float* b_out = (const float*)d_in[13];

    float* wsf   = (float*)d_ws;
    int*   tok   = (int*)d_ws;
    float* shiftb= wsf + OFF_SHIFT;
    float* Wv    = wsf + OFF_WV;
    float* hxT   = wsf + OFF_HXT;
    float* xo    = wsf + OFF_XO;
    float* hxB   = wsf + OFF_CX;
    float* den   = wsf + OFF_DEN;
    float* q     = wsf + OFF_Q;
    float* ctxT  = wsf + OFF_CTX;
    float* obuf  = wsf + OFF_OBUF;
    int*   bar   = (int*)(wsf + OFF_BAR);

    float* out_logits = (float*)d_out;
    float* out_alphas = (float*)d_out + LOGITS_SZ;

    k_setup<<<96, 256, 0, stream>>>(tgt, vv, hxT, bar, tok, shiftb);
    k_embx<<<(Ss * 8192 + 255) / 256, 256, 0, stream>>>(emb, tok, obuf);
    k_wv<<<768, 256, 0, stream>>>(enc, W_v, Wv);
    k_decode<<<NBLK, NTHR, 0, stream>>>(enc, W_ih, b_ih, W_hh, b_hh, W_h, vv,
                                        W_c, b_c, Wv, shiftb,
                                        hxT, xo, hxB, den, q, ctxT, obuf,
                                        out_alphas, bar);
    k_logits<<<768, 256, 0, stream>>>(obuf, W_out, b_out, out_logits);
    k_anorm<<<(ALPHA_SZ + 255) / 256, 256, 0, stream>>>(out_alphas, den);
}

// Round 9
// 5164.139 us; speedup vs baseline: 3.4698x; 1.6044x over previous
//
#include <hip/hip_runtime.h>
#include <cstdint>

#define Bb 32
#define Cc 512
#define Nn 384
#define Vv 600
#define Ee 256
#define Dd 512
#define Tt 192
#define Ss 191
#define EOS_TOK 130
#define BD (Bb*Dd)          // 16384
#define NBLK 256
#define NTHR 512

// ---- ws layout (float offsets) ----
#define OFF_TOK   0                      // int tok[Ss*Bb]
#define OFF_SHIFT 8192                   // float shift[1]
#define OFF_WV    8256                   // Bb*Nn*Dd = 6291456
#define OFF_HXT   6299712                // 2*16384 hxT [par][d][b] (sc1)
#define OFF_XO    6332480                // 16384 xo [d][b] (sc1)
#define OFF_HXB   6348864                // 16384 hxB [b][d] (sc1)
#define OFF_DEN   6365248                // den[t][b] 191*32 (pad 8192, zeroed once)
#define OFF_Q     6373440                // q[b][d] 32*512 (sc1)
#define OFF_CTXB  6389824                // ctxB[b][c] 32*512 (atomics + sc1)
#define OFF_OBUF  6406208                // 192*BD; slot t+1 front doubles as embx[t]
#define OFF_BAR   9551936                // flags[256*16]+genv[32*16]+qdone[256*16]+dedone[256*16]

#define LOGITS_SZ (Bb*Ss*Vv)  // 3667200
#define ALPHA_SZ  (Bb*Ss*Nn)  // 2347008

__device__ __forceinline__ float sigm_(float x) {
    float e = __expf(-x);
    return __builtin_amdgcn_rcpf(1.0f + e);
}
__device__ __forceinline__ float tanh_(float x) {
    float xc = fminf(15.0f, fmaxf(-15.0f, x));
    float e = __expf(2.0f * xc);
    return (e - 1.0f) * __builtin_amdgcn_rcpf(e + 1.0f);
}

// Write-through device store (sc1): at LLC once vmcnt retires; __syncthreads
// drains vmcnt, so no release fence is ever needed.
__device__ __forceinline__ void st_dev(float* p, float v) {
    __hip_atomic_store(p, v, __ATOMIC_RELAXED, __HIP_MEMORY_SCOPE_AGENT);
}
__device__ __forceinline__ float ld1_dev(const float* p) {
    return __hip_atomic_load(p, __ATOMIC_RELAXED, __HIP_MEMORY_SCOPE_AGENT);
}
// 8-byte coherent load (sc1 bypass, relaxed).
__device__ __forceinline__ float2 ld2_dev(const float* p) {
    unsigned long long u = __hip_atomic_load((const unsigned long long*)p,
                                             __ATOMIC_RELAXED,
                                             __HIP_MEMORY_SCOPE_AGENT);
    float2 f;
    f.x = __uint_as_float((unsigned int)u);
    f.y = __uint_as_float((unsigned int)(u >> 32));
    return f;
}

// Flag-array device barrier (proven aggregator protocol, unchanged).
__device__ __forceinline__ void gbar(int* flags, int* genv, int ibar) {
    __syncthreads();   // drains vmcnt: all sc1 data stores ack'd at LLC
    const int target = ibar + 1;
    if (threadIdx.x == 0)
        __hip_atomic_store(&flags[blockIdx.x * 16], target, __ATOMIC_RELAXED,
                           __HIP_MEMORY_SCOPE_AGENT);
    if (blockIdx.x == 0) {
        if (threadIdx.x < 64) {
            int l = threadIdx.x * 4;
            for (;;) {
                int f0 = __hip_atomic_load(&flags[(l + 0) * 16], __ATOMIC_RELAXED,
                                           __HIP_MEMORY_SCOPE_AGENT);
                int f1 = __hip_atomic_load(&flags[(l + 1) * 16], __ATOMIC_RELAXED,
                                           __HIP_MEMORY_SCOPE_AGENT);
                int f2 = __hip_atomic_load(&flags[(l + 2) * 16], __ATOMIC_RELAXED,
                                           __HIP_MEMORY_SCOPE_AGENT);
                int f3 = __hip_atomic_load(&flags[(l + 3) * 16], __ATOMIC_RELAXED,
                                           __HIP_MEMORY_SCOPE_AGENT);
                if (__all(f0 >= target && f1 >= target &&
                          f2 >= target && f3 >= target)) break;
                __builtin_amdgcn_s_sleep(1);
            }
            if (threadIdx.x < 32)
                __hip_atomic_store(&genv[threadIdx.x * 16], target,
                                   __ATOMIC_RELAXED, __HIP_MEMORY_SCOPE_AGENT);
        }
    } else if (threadIdx.x == 0) {
        int* g = &genv[(blockIdx.x >> 3) * 16];
        while (__hip_atomic_load(g, __ATOMIC_RELAXED,
                                 __HIP_MEMORY_SCOPE_AGENT) < target)
            __builtin_amdgcn_s_sleep(2);
    }
    __syncthreads();
}

// 8-flag group poll: lane l (0..63) polls flag (grp*8 + (l&7)); divergent
// spin, reconverges when all lanes' flags reach target.
__device__ __forceinline__ void poll8(int* base, int grp, int target) {
    if (threadIdx.x < 64) {
        int* g = &base[(grp * 8 + (threadIdx.x & 7)) * 16];
        while (__hip_atomic_load(g, __ATOMIC_RELAXED,
                                 __HIP_MEMORY_SCOPE_AGENT) < target)
            __builtin_amdgcn_s_sleep(1);
    }
    __syncthreads();
}

// S0: zero state/flags/denoms, token sequence, exp-shift = sum|v|.
__global__ void k_setup(const int* __restrict__ tgt, const float* __restrict__ vv,
                        float* zbase, int* bar, int* tok, float* shiftbuf) {
    int gid = blockIdx.x * 256 + threadIdx.x;
    for (int i = gid; i < 73728; i += 96 * 256) zbase[i] = 0.f;   // hxT,xo,hxB,den
    if (gid < 12800) bar[gid] = 0;  // flags+genv+qdone+dedone
    if (blockIdx.x == 0) {
        __shared__ int is64;
        if (threadIdx.x == 0) {
            int a = 1;
            for (int k = 0; k < 32; ++k) if (tgt[2 * k + 1] != 0) a = 0;
            is64 = a;
        }
        __syncthreads();
        int b = threadIdx.x;
        if (b < Bb) {
            int fin = 0;
            tok[0 * Bb + b] = 0;
            for (int s = 1; s < Ss; ++s) {
                int li = b * Tt + s;
                int nt = is64 ? tgt[2 * li] : tgt[li];
                if (nt == EOS_TOK) fin = 1;
                tok[s * Bb + b] = fin ? 0 : nt;
            }
        }
    }
    if (blockIdx.x == 1) {
        __shared__ float sred[256];
        int tid = threadIdx.x;
        sred[tid] = fabsf(vv[tid]) + fabsf(vv[tid + 256]);
        __syncthreads();
        for (int s = 128; s > 0; s >>= 1) {
            if (tid < s) sred[tid] += sred[tid + s];
            __syncthreads();
        }
        if (tid == 0) shiftbuf[0] = sred[0];
    }
}

// S1: gather embeddings for all steps into obuf slot fronts: [t][k][b]
__global__ void k_embx(const float* __restrict__ emb, const int* __restrict__ tok,
                       float* __restrict__ obuf) {
    int i = blockIdx.x * 256 + threadIdx.x;
    if (i < Ss * 8192) {
        int t = i >> 13, e = i & 8191;
        int k = e >> 5, b = e & 31;
        obuf[(size_t)(t + 1) * BD + e] = emb[(size_t)tok[t * 32 + b] * Ee + k];
    }
}

// S2: Wv[b,n,d] = sum_c enc[b,n,c] * W_v[c,d]
__global__ void k_wv(const float* __restrict__ enc, const float* __restrict__ Wv_w,
                     float* __restrict__ Wv) {
    int b = blockIdx.x / 24, nt = blockIdx.x % 24, n0 = nt * 16;
    __shared__ float encL[16 * 512];
    for (int i = 0; i < 32; ++i) {
        int e = threadIdx.x + i * 256;
        int ni = e >> 9, c = e & 511;
        encL[e] = enc[((b * Nn) + (n0 + ni)) * Cc + c];
    }
    __syncthreads();
    int d0 = threadIdx.x, d1 = threadIdx.x + 256;
    float a0[16], a1[16];
#pragma unroll
    for (int i = 0; i < 16; ++i) { a0[i] = 0.f; a1[i] = 0.f; }
    for (int c = 0; c < 512; ++c) {
        float w0 = Wv_w[c * Dd + d0], w1 = Wv_w[c * Dd + d1];
#pragma unroll
        for (int i = 0; i < 16; ++i) {
            float ev = encL[i * 512 + c];
            a0[i] += ev * w0; a1[i] += ev * w1;
        }
    }
#pragma unroll
    for (int i = 0; i < 16; ++i) {
        Wv[((b * Nn) + (n0 + i)) * Dd + d0] = a0[i];
        Wv[((b * Nn) + (n0 + i)) * Dd + d1] = a1[i];
    }
}

// Persistent decode: 256 blocks x 512 threads.
// Per step: A (dim-distributed, LDS weights) -> gbar -> C (batch x col-slice,
// L2-resident W_h slice) -> qdone flags -> DE -> dedone flags -> F (batch x
// col-slice, L2-resident W_c slice) -> gbar.  2 global barriers + 2 light
// flag handoffs replace r3's 4 global barriers.
__global__ __launch_bounds__(NTHR) void k_decode(
    const float* __restrict__ enc, const float* __restrict__ W_ih,
    const float* __restrict__ b_ih, const float* __restrict__ W_hh,
    const float* __restrict__ b_hh, const float* __restrict__ W_h,
    const float* __restrict__ vv, const float* __restrict__ W_c,
    const float* __restrict__ b_c, const float* __restrict__ Wv,
    const float* __restrict__ shiftbuf,
    float* __restrict__ hxT, float* __restrict__ xo, float* __restrict__ hxB,
    float* __restrict__ den, float* __restrict__ q, float* __restrict__ ctxB,
    float* __restrict__ obuf, float* __restrict__ alpha_e, int* bar)
{
    __shared__ float Wg[1280 * 8];    // A: gate cols [k][g*2+dd]  40960B
    __shared__ float scratch[8192];   // phase-local               32768B
    __shared__ float cxL[64];         // block-private cell state

    int* flags  = bar;
    int* genv   = bar + 4096;
    int* qdone  = bar + 4608;
    int* dedone = bar + 8704;

    const int tid = threadIdx.x, bid = blockIdx.x;
    const int lane = tid & 63;
    const int d0 = bid * 2;           // A dims
    const int bp = tid & 15;          // A: b-pair
    const int ab = bid >> 3;          // DE/C/F: batch
    const int n0 = (bid & 7) * 48;    // DE: n-slice
    const int cg = bid & 7;           // C/F: col-group (64 cols)
    const int w  = tid >> 6;          // wave id

    // ---- one-time staging ----
    for (int k = tid; k < 1280; k += NTHR) {
        const float* src = (k < 768) ? (W_ih + (size_t)k * 2048)
                                     : (W_hh + (size_t)(k - 768) * 2048);
#pragma unroll
        for (int g = 0; g < 4; ++g) {
            Wg[k * 8 + g * 2 + 0] = src[g * 512 + d0 + 0];
            Wg[k * 8 + g * 2 + 1] = src[g * 512 + d0 + 1];
        }
    }
    if (tid < 64) cxL[tid] = 0.f;
    float v8[8];
#pragma unroll
    for (int i = 0; i < 8; ++i) v8[i] = vv[lane * 8 + i];
    float4 wva[6], wvb[6];            // t-invariant Wv fragment
#pragma unroll
    for (int r = 0; r < 6; ++r) {
        const float* wv = Wv + ((size_t)(ab * Nn + n0 + w * 6 + r)) * 512 + lane * 8;
        wva[r] = *(const float4*)wv;
        wvb[r] = *(const float4*)(wv + 4);
    }
    float encR[48];                   // t-invariant enc column slice
#pragma unroll
    for (int i = 0; i < 48; ++i)
        encR[i] = enc[((size_t)(ab * Nn + n0 + i)) * 512 + tid];
    const float SHIFT = shiftbuf[0];
    const float bcF = b_c[cg * 64 + (tid & 63)];
    float bsum0 = 0.f, bsum1 = 0.f, bsum2 = 0.f, bsum3 = 0.f;
    if (tid < 64) {
        int dd = tid >> 5;
        int d = d0 + dd;
        bsum0 = b_ih[0 * 512 + d] + b_hh[0 * 512 + d];
        bsum1 = b_ih[1 * 512 + d] + b_hh[1 * 512 + d];
        bsum2 = b_ih[2 * 512 + d] + b_hh[2 * 512 + d];
        bsum3 = b_ih[3 * 512 + d] + b_hh[3 * 512 + d];
    }
    __syncthreads();

    int ib = 0;
    for (int t = 0; t < Ss; ++t) {
        const int rd = t & 1, wr = 1 - rd;
        const float* hxT_rd = hxT + rd * 16384;
        float*       hxT_wr = hxT + wr * 16384;

        // ---------- Phase A: gates (full K) + LSTM + ctx-zero ----------
        {
            // zero this block's ctxB slice for THIS step's DE atomics
            // (safe: A(t) runs after gbar2(t-1), which follows F(t-1)'s reads)
            if (tid < 64)
                st_dev(&ctxB[bid * 64 + tid], 0.f);
            const float* embx_t = obuf + (size_t)(t + 1) * BD;  // [k][b], k<256
            const float* xo2 = xo - 256 * 32;
            const float* hx2 = hxT_rd - 768 * 32;
            int ks = tid >> 4;           // 32 k-chunks of 40
            int k0 = ks * 40;
            float ax[8], ay[8];
#pragma unroll
            for (int i = 0; i < 8; ++i) { ax[i] = 0.f; ay[i] = 0.f; }
            if (t) {
#pragma unroll
                for (int kb = 0; kb < 5; ++kb) {
                    int kbase = k0 + kb * 8;
                    float2 xv[8];
#pragma unroll
                    for (int j = 0; j < 8; ++j) {      // 8 outstanding sc1 loads
                        int k = kbase + j;
                        const float* base = (k < 256) ? embx_t : ((k < 768) ? xo2 : hx2);
                        xv[j] = ld2_dev(base + k * 32 + 2 * bp);
                    }
#pragma unroll
                    for (int j = 0; j < 8; ++j) {
                        int k = kbase + j;
                        float4 wA = *(const float4*)&Wg[k * 8];
                        float4 wB = *(const float4*)&Wg[k * 8 + 4];
                        ax[0] += xv[j].x * wA.x; ay[0] += xv[j].y * wA.x;
                        ax[1] += xv[j].x * wA.y; ay[1] += xv[j].y * wA.y;
                        ax[2] += xv[j].x * wA.z; ay[2] += xv[j].y * wA.z;
                        ax[3] += xv[j].x * wA.w; ay[3] += xv[j].y * wA.w;
                        ax[4] += xv[j].x * wB.x; ay[4] += xv[j].y * wB.x;
                        ax[5] += xv[j].x * wB.y; ay[5] += xv[j].y * wB.y;
                        ax[6] += xv[j].x * wB.z; ay[6] += xv[j].y * wB.z;
                        ax[7] += xv[j].x * wB.w; ay[7] += xv[j].y * wB.w;
                    }
                }
            }
#pragma unroll
            for (int c = 0; c < 8; ++c) {
                scratch[(ks * 8 + c) * 32 + 2 * bp]     = ax[c];
                scratch[(ks * 8 + c) * 32 + 2 * bp + 1] = ay[c];
            }
            __syncthreads();
            if (tid < 256) {
                int col = tid >> 5, b2 = tid & 31;
                float s = 0.f;
#pragma unroll
                for (int k2 = 0; k2 < 32; ++k2) s += scratch[(k2 * 8 + col) * 32 + b2];
                scratch[col * 32 + b2] = s;
            }
            __syncthreads();
            if (tid < 64) {
                int dd = tid >> 5, b2 = tid & 31;
                float gi = scratch[(0 * 2 + dd) * 32 + b2] + bsum0;
                float gf = scratch[(1 * 2 + dd) * 32 + b2] + bsum1;
                float gg = scratch[(2 * 2 + dd) * 32 + b2] + bsum2;
                float go = scratch[(3 * 2 + dd) * 32 + b2] + bsum3;
                float c = sigm_(gf) * cxL[tid] + sigm_(gi) * tanh_(gg);
                cxL[tid] = c;
                float h = sigm_(go) * tanh_(c);
                st_dev(&hxT_wr[(d0 + dd) * 32 + b2], h);
                st_dev(&hxB[b2 * 512 + d0 + dd], h);   // row-major copy for C/F
            }
        }
        gbar(flags, genv, ib++);

        // ---------- Phase C: q[ab][cg*64..+64) = hx[ab] @ W_h slice ----------
        {
            float* hxL  = scratch;          // 512
            float* gred = scratch + 512;    // 8*72
            hxL[tid] = ld1_dev(&hxB[ab * 512 + tid]);
            __syncthreads();
            int col = tid & 63, kseg = tid >> 6;   // kseg == wave id
            const float* wp = W_h + (size_t)(kseg * 64) * 512 + cg * 64 + col;
            const float* xr = hxL + kseg * 64;
            float a = 0.f;
#pragma unroll 8
            for (int kk = 0; kk < 64; ++kk)
                a += wp[(size_t)kk * 512] * xr[kk];
            gred[kseg * 72 + col] = a;
            __syncthreads();
            if (tid < 64) {
                float s = 0.f;
#pragma unroll
                for (int k2 = 0; k2 < 8; ++k2) s += gred[k2 * 72 + tid];
                st_dev(&q[ab * 512 + cg * 64 + tid], s);
            }
            __syncthreads();   // drain q stores
            if (tid == 0)
                __hip_atomic_store(&qdone[bid * 16], t + 1, __ATOMIC_RELAXED,
                                   __HIP_MEMORY_SCOPE_AGENT);
        }

        // ---------- Phase DE: poll q flags, scores + exp + ctx atomics ----------
        {
            poll8(qdone, ab, t + 1);
            float* esc = scratch;            // 48 e-values
            float q8[8];
#pragma unroll
            for (int j = 0; j < 4; ++j) {
                float2 qv = ld2_dev(&q[ab * 512 + lane * 8 + 2 * j]);
                q8[2 * j] = qv.x; q8[2 * j + 1] = qv.y;
            }
#pragma unroll
            for (int r = 0; r < 6; ++r) {
                float s = v8[0] * tanh_(q8[0] + wva[r].x) + v8[1] * tanh_(q8[1] + wva[r].y)
                        + v8[2] * tanh_(q8[2] + wva[r].z) + v8[3] * tanh_(q8[3] + wva[r].w)
                        + v8[4] * tanh_(q8[4] + wvb[r].x) + v8[5] * tanh_(q8[5] + wvb[r].y)
                        + v8[6] * tanh_(q8[6] + wvb[r].z) + v8[7] * tanh_(q8[7] + wvb[r].w);
#pragma unroll
                for (int off = 32; off > 0; off >>= 1)
                    s += __shfl_down(s, off, 64);
                if (lane == 0) esc[w * 6 + r] = __expf(s - SHIFT);
            }
            __syncthreads();
            if (tid < 48)
                alpha_e[((size_t)ab * Ss + t) * Nn + n0 + tid] = esc[tid];
            if (tid == 0) {
                float sd = 0.f;
                for (int i = 0; i < 48; ++i) sd += esc[i];
                atomicAdd(&den[t * 32 + ab], sd);
            }
            float acc = 0.f;
#pragma unroll 8
            for (int i = 0; i < 48; ++i)
                acc += esc[i] * encR[i];
            atomicAdd(&ctxB[ab * 512 + tid], acc);
            __syncthreads();   // drain atomics
            if (tid == 0)
                __hip_atomic_store(&dedone[bid * 16], t + 1, __ATOMIC_RELAXED,
                                   __HIP_MEMORY_SCOPE_AGENT);
        }

        // ---------- Phase F: o[ab][cg*64..+64) = tanh([hx|ctx/den] @ W_c slice + b_c) ----------
        {
            poll8(dedone, ab, t + 1);
            float* xF   = scratch;          // 1024
            float* gred = scratch + 1024;   // 8*72
            float rdn = 1.0f / ld1_dev(&den[t * 32 + ab]);
            xF[tid]       = ld1_dev(&hxB[ab * 512 + tid]);
            xF[512 + tid] = ld1_dev(&ctxB[ab * 512 + tid]) * rdn;
            __syncthreads();
            int col = tid & 63, kseg = tid >> 6;
            const float* wp = W_c + (size_t)(kseg * 128) * 512 + cg * 64 + col;
            const float* xr = xF + kseg * 128;
            float a = 0.f;
#pragma unroll 8
            for (int kk = 0; kk < 128; ++kk)
                a += wp[(size_t)kk * 512] * xr[kk];
            gred[kseg * 72 + col] = a;
            __syncthreads();
            if (tid < 64) {
                float s = bcF;
#pragma unroll
                for (int k2 = 0; k2 < 8; ++k2) s += gred[k2 * 72 + tid];
                float o = tanh_(s);
                st_dev(&xo[(cg * 64 + tid) * 32 + ab], o);
                obuf[(size_t)(t + 1) * BD + ab * 512 + cg * 64 + tid] = o;
            }
        }
        gbar(flags, genv, ib++);
    }
}

// Deferred logits GEMM.
__global__ void k_logits(const float* __restrict__ obuf, const float* __restrict__ W_out,
                         const float* __restrict__ b_out, float* __restrict__ out_logits) {
    int b = blockIdx.x / 24, tt = blockIdx.x % 24;
    int t0 = tt * 8;
    int tmax = min(8, Ss - t0);
    __shared__ float oL[8 * 512];
    int tid = threadIdx.x;
    for (int i = 0; i < 16; ++i) {
        int e = tid + i * 256;
        int ti = e >> 9, d = e & 511;
        oL[e] = (ti < tmax) ? obuf[(size_t)(t0 + ti + 1) * BD + b * Dd + d] : 0.f;
    }
    __syncthreads();
    int v0 = tid, v1 = tid + 256, v2 = tid + 512;
    bool h2 = (v2 < Vv);
    int v2c = h2 ? v2 : 0;
    float acc[3][8];
#pragma unroll
    for (int s = 0; s < 3; ++s)
#pragma unroll
        for (int ti = 0; ti < 8; ++ti) acc[s][ti] = 0.f;
    for (int d = 0; d < 512; ++d) {
        float w0 = W_out[d * Vv + v0];
        float w1 = W_out[d * Vv + v1];
        float w2 = W_out[d * Vv + v2c];
#pragma unroll
        for (int ti = 0; ti < 8; ++ti) {
            float o = oL[ti * 512 + d];
            acc[0][ti] += o * w0; acc[1][ti] += o * w1; acc[2][ti] += o * w2;
        }
    }
    for (int ti = 0; ti < tmax; ++ti) {
        size_t base = (size_t)b * (Ss * Vv) + (size_t)(t0 + ti) * Vv;
        out_logits[base + v0] = acc[0][ti] + b_out[v0];
        out_logits[base + v1] = acc[1][ti] + b_out[v1];
        if (h2) out_logits[base + v2] = acc[2][ti] + b_out[v2];
    }
}

// Normalize alphas: alpha /= denom[b,t]
__global__ void k_anorm(float* __restrict__ alph, const float* __restrict__ den) {
    int i = blockIdx.x * 256 + threadIdx.x;
    if (i < ALPHA_SZ) {
        int bt = i / Nn;
        int t = bt % Ss, b = bt / Ss;
        alph[i] = alph[i] / den[t * 32 + b];
    }
}

extern "C" void kernel_launch(void* const* d_in, const int* in_sizes, int n_in,
                              void* d_out, int out_size, void* d_ws, size_t ws_size,
                              hipStream_t stream) {
    const float* enc   = (const float*)d_in[0];
    const int*   tgt   = (const int*)d_in[1];
    const float* emb   = (const float*)d_in[2];
    const float* W_ih  = (const float*)d_in[3];
    const float* b_ih  = (const float*)d_in[4];
    const float* W_hh  = (const float*)d_in[5];
    const float* b_hh  = (const float*)d_in[6];
    const float* W_h   = (const float*)d_in[7];
    const float* W_v   = (const float*)d_in[8];
    const float* vv    = (const float*)d_in[9];
    const float* W_c   = (const float*)d_in[10];
    const float* b_c   = (const float*)d_in[11];
    const float* W_out = (const float*)d_in[12];
    const float* b_out = (const float*)d_in[13];

    float* wsf   = (float*)d_ws;
    int*   tok   = (int*)d_ws;
    float* shiftb= wsf + OFF_SHIFT;
    float* Wv    = wsf + OFF_WV;
    float* hxT   = wsf + OFF_HXT;
    float* xo    = wsf + OFF_XO;
    float* hxB   = wsf + OFF_HXB;
    float* den   = wsf + OFF_DEN;
    float* q     = wsf + OFF_Q;
    float* ctxB  = wsf + OFF_CTXB;
    float* obuf  = wsf + OFF_OBUF;
    int*   bar   = (int*)(wsf + OFF_BAR);

    float* out_logits = (float*)d_out;
    float* out_alphas = (float*)d_out + LOGITS_SZ;

    k_setup<<<96, 256, 0, stream>>>(tgt, vv, hxT, bar, tok, shiftb);
    k_embx<<<(Ss * 8192 + 255) / 256, 256, 0, stream>>>(emb, tok, obuf);
    k_wv<<<768, 256, 0, stream>>>(enc, W_v, Wv);
    k_decode<<<NBLK, NTHR, 0, stream>>>(enc, W_ih, b_ih, W_hh, b_hh, W_h, vv,
                                        W_c, b_c, Wv, shiftb,
                                        hxT, xo, hxB, den, q, ctxB, obuf,
                                        out_alphas, bar);
    k_logits<<<768, 256, 0, stream>>>(obuf, W_out, b_out, out_logits);
    k_anorm<<<(ALPHA_SZ + 255) / 256, 256, 0, stream>>>(out_alphas, den);
}